// Round 13
// baseline (216.216 us; speedup 1.0000x reference)
//
#include <hip/hip_runtime.h>
#include <math.h>

#define B_ 8
#define S_ 2048
#define D_ 1024
#define H_ 16
#define A_ 4
#define DA_ 64
#define LN_EPS 1e-5f
// 0.125 * log2(e): Q pre-scale so softmax runs in exp2 domain
#define QSCALE 0.1803368801111204f
// fixed softmax reference (log2 units)
#define MREF 20.0f

typedef __bf16 bf16x8 __attribute__((ext_vector_type(8)));
typedef __bf16 bf16x4 __attribute__((ext_vector_type(4)));
typedef float f32x4 __attribute__((ext_vector_type(4)));
typedef unsigned short u16x8 __attribute__((ext_vector_type(8)));

// ---------------- workspace layout (bytes) ----------------
static const size_t OFF_PARTIAL = 0;
static const size_t OFF_LPART   = 0;
static const size_t OFF_IDX     = (size_t)1 << 20;
static const size_t OFF_DIST    = ((size_t)1 << 20) + 1024;
static const size_t OFF_WOT     = ((size_t)1 << 20) + ((size_t)1 << 19);
static const size_t OFF_XB      = (size_t)2 << 20;
static const size_t OFF_OPART   = OFF_XB;
static const size_t OFF_WT      = (size_t)34 << 20;
static const size_t OFF_Q       = (size_t)40 << 20;
static const size_t OFF_OFIN    = OFF_Q;
static const size_t OFF_K       = (size_t)48 << 20;
static const size_t OFF_V       = (size_t)56 << 20;

// ---------------- kernel 1: column-sum partial over S + bf16 convert ----------------
__global__ __launch_bounds__(256) void k_partial(const float* __restrict__ x,
                                                 float* __restrict__ partial,
                                                 __bf16* __restrict__ xb) {
  const int c = blockIdx.x, b = blockIdx.y, t = threadIdx.x;
  const size_t base = ((size_t)b * S_ + (size_t)c * 64) * D_;
  f32x4 acc = {0.f, 0.f, 0.f, 0.f};
  for (int s = 0; s < 64; ++s) {
    f32x4 v = *(const f32x4*)(x + base + (size_t)s * D_ + 4 * t);
    acc += v;
    bf16x4 o;
    #pragma unroll
    for (int j = 0; j < 4; ++j) o[j] = (__bf16)v[j];
    *(bf16x4*)(xb + base + (size_t)s * D_ + 4 * t) = o;
  }
  *(f32x4*)(partial + ((size_t)b * 32 + c) * D_ + 4 * t) = acc;
}

// ---------------- kernel 1b: transpose QKV weights to bf16 [m][n][k] ----------------
__global__ __launch_bounds__(256) void k_wt(const float* __restrict__ Wq,
                                            const float* __restrict__ Wk,
                                            const float* __restrict__ Wv,
                                            __bf16* __restrict__ Wt) {
  __shared__ float tsh[64][65];
  const int n0 = blockIdx.x * 64, k0 = blockIdx.y * 64, z = blockIdx.z;
  const float* W = (z == 0) ? Wq : (z == 1) ? Wk : Wv;
  const int t = threadIdx.x;
  #pragma unroll
  for (int i = 0; i < 4; ++i) {
    int r = i * 16 + (t >> 4), c = (t & 15) * 4;
    f32x4 v = *(const f32x4*)(W + (size_t)(k0 + r) * (H_ * DA_) + n0 + c);
    tsh[r][c + 0] = v[0]; tsh[r][c + 1] = v[1]; tsh[r][c + 2] = v[2]; tsh[r][c + 3] = v[3];
  }
  __syncthreads();
  #pragma unroll
  for (int i = 0; i < 4; ++i) {
    int n = i * 16 + (t >> 4), kc = (t & 15) * 4;
    bf16x4 o;
    #pragma unroll
    for (int j = 0; j < 4; ++j) o[j] = (__bf16)tsh[kc + j][n];
    *(bf16x4*)(Wt + (size_t)z * 1048576 + (size_t)(n0 + n) * 1024 + k0 + kc) = o;
  }
}

// ---------------- kernel 1c: transpose Wo [256][1024] -> WoT bf16 [1024][256] ----------------
__global__ __launch_bounds__(256) void k_wto(const float* __restrict__ Wo,
                                             __bf16* __restrict__ WoT) {
  __shared__ float tsh[64][65];
  const int n0 = blockIdx.x * 64, k0 = blockIdx.y * 64;
  const int t = threadIdx.x;
  #pragma unroll
  for (int i = 0; i < 4; ++i) {
    int r = i * 16 + (t >> 4), c = (t & 15) * 4;
    f32x4 v = *(const f32x4*)(Wo + (size_t)(k0 + r) * D_ + n0 + c);
    tsh[r][c + 0] = v[0]; tsh[r][c + 1] = v[1]; tsh[r][c + 2] = v[2]; tsh[r][c + 3] = v[3];
  }
  __syncthreads();
  #pragma unroll
  for (int i = 0; i < 4; ++i) {
    int n = i * 16 + (t >> 4), kc = (t & 15) * 4;
    bf16x4 o;
    #pragma unroll
    for (int j = 0; j < 4; ++j) o[j] = (__bf16)tsh[kc + j][n];
    *(bf16x4*)(WoT + (size_t)(n0 + n) * (A_ * DA_) + k0 + kc) = o;
  }
}

// ---------------- kernel 2: xbar -> r -> LN -> softmax -> top4 ----------------
__global__ __launch_bounds__(256) void k_stats(const float* __restrict__ partial,
                                               const float* __restrict__ Wr,
                                               const float* __restrict__ br,
                                               const float* __restrict__ gamma,
                                               const float* __restrict__ beta,
                                               int* __restrict__ idx_out,
                                               float* __restrict__ dist_out) {
  __shared__ float xbar[D_];
  __shared__ float rsh[H_];
  const int b = blockIdx.x, t = threadIdx.x;
  #pragma unroll
  for (int j = 0; j < 4; ++j) {
    int d = j * 256 + t;
    float s = 0.f;
    for (int c = 0; c < 32; ++c) s += partial[((size_t)b * 32 + c) * D_ + d];
    xbar[d] = s * (1.0f / S_);
  }
  __syncthreads();
  const int w = t >> 6, lane = t & 63;
  #pragma unroll
  for (int i = 0; i < 4; ++i) {
    int h = w * 4 + i;
    float s = 0.f;
    #pragma unroll
    for (int j = 0; j < 16; ++j) {
      int d = j * 64 + lane;
      s += xbar[d] * Wr[d * H_ + h];
    }
    for (int off = 32; off; off >>= 1) s += __shfl_down(s, off);
    if (lane == 0) rsh[h] = s + br[h];
  }
  __syncthreads();
  if (t == 0) {
    float r[H_];
    float mu = 0.f;
    for (int h = 0; h < H_; ++h) { r[h] = rsh[h]; mu += r[h]; }
    mu *= (1.0f / H_);
    float var = 0.f;
    for (int h = 0; h < H_; ++h) { float d = r[h] - mu; var += d * d; }
    var *= (1.0f / H_);
    float inv = rsqrtf(var + LN_EPS);
    float rn[H_], ex[H_];
    float mx = -1e30f;
    for (int h = 0; h < H_; ++h) {
      rn[h] = (r[h] - mu) * inv * gamma[h] + beta[h];
      mx = fmaxf(mx, rn[h]);
    }
    float sum = 0.f;
    for (int h = 0; h < H_; ++h) { ex[h] = expf(rn[h] - mx); sum += ex[h]; }
    int sel[A_];
    bool used[H_] = {false};
    for (int a = 0; a < A_; ++a) {
      int best = 0; float bv = -1.f;
      for (int h = 0; h < H_; ++h)
        if (!used[h] && ex[h] > bv) { bv = ex[h]; best = h; }
      used[best] = true; sel[a] = best;
    }
    for (int i = 0; i < A_; ++i)
      for (int j = i + 1; j < A_; ++j)
        if (sel[j] < sel[i]) { int tmp = sel[i]; sel[i] = sel[j]; sel[j] = tmp; }
    float invsum = 1.0f / sum;
    for (int a = 0; a < A_; ++a) {
      idx_out[b * A_ + a] = sel[a];
      dist_out[b * A_ + a] = ex[sel[a]] * invsum;
    }
  }
}

// ---------------- kernel 3: QKV projection, bf16 MFMA ----------------
// grid (S/64=32, B*A=32) = 1024 blocks (4/CU), block 256 (4 waves).
// Tile 64(M) x 192(N), BK=64. Wave owns 32x96 (2x6 frags). Async reg
// double-buffer staging. Q pre-scaled by QSCALE.
__global__ __launch_bounds__(256) void k_qkv_mfma(const __bf16* __restrict__ xb,
                                                  const __bf16* __restrict__ Wt,
                                                  const float* __restrict__ bq,
                                                  const float* __restrict__ bk,
                                                  const float* __restrict__ bv,
                                                  const int* __restrict__ idx,
                                                  __bf16* __restrict__ Q,
                                                  __bf16* __restrict__ K,
                                                  __bf16* __restrict__ V) {
  __shared__ unsigned short As[64][72];
  __shared__ unsigned short Bs[192][72];
  const int qt = blockIdx.x, ba = blockIdx.y;
  const int b = ba >> 2;
  const int head64 = idx[ba] * 64;
  const int t = threadIdx.x;
  const int w = t >> 6, l = t & 63, x = l & 15, g = l >> 4;
  const int MO = (w >> 1) * 32, NO = (w & 1) * 96;

  const unsigned short* xbu = (const unsigned short*)xb;
  const unsigned short* Wtu = (const unsigned short*)Wt;
  const size_t xbase = ((size_t)b * S_ + (size_t)qt * 64) * D_;

  u16x8 areg[2], breg[6];
  #pragma unroll
  for (int i = 0; i < 2; ++i) {
    int id = t + 256 * i, row = id >> 3, ch = id & 7;
    areg[i] = *(const u16x8*)(xbu + xbase + (size_t)row * D_ + ch * 8);
  }
  #pragma unroll
  for (int i = 0; i < 6; ++i) {
    int id = t + 256 * i, row = id >> 3, ch = id & 7;
    int m = row >> 6, nn = row & 63;
    breg[i] = *(const u16x8*)(Wtu + (size_t)m * 1048576 +
                              (size_t)(head64 + nn) * 1024 + ch * 8);
  }

  f32x4 acc[2][6];
  #pragma unroll
  for (int mf = 0; mf < 2; ++mf)
    #pragma unroll
    for (int nf = 0; nf < 6; ++nf) acc[mf][nf] = (f32x4){0.f, 0.f, 0.f, 0.f};

  for (int k0 = 0; k0 < D_; k0 += 64) {
    __syncthreads();
    #pragma unroll
    for (int i = 0; i < 2; ++i) {
      int id = t + 256 * i, row = id >> 3, ch = id & 7;
      *(u16x8*)&As[row][ch * 8] = areg[i];
    }
    #pragma unroll
    for (int i = 0; i < 6; ++i) {
      int id = t + 256 * i, row = id >> 3, ch = id & 7;
      *(u16x8*)&Bs[row][ch * 8] = breg[i];
    }
    __syncthreads();
    {
      int kn = (k0 + 64 < D_) ? k0 + 64 : k0;
      #pragma unroll
      for (int i = 0; i < 2; ++i) {
        int id = t + 256 * i, row = id >> 3, ch = id & 7;
        areg[i] = *(const u16x8*)(xbu + xbase + (size_t)row * D_ + kn + ch * 8);
      }
      #pragma unroll
      for (int i = 0; i < 6; ++i) {
        int id = t + 256 * i, row = id >> 3, ch = id & 7;
        int m = row >> 6, nn = row & 63;
        breg[i] = *(const u16x8*)(Wtu + (size_t)m * 1048576 +
                                  (size_t)(head64 + nn) * 1024 + kn + ch * 8);
      }
    }
    #pragma unroll
    for (int ks = 0; ks < 2; ++ks) {
      bf16x8 af[2], bfr[6];
      #pragma unroll
      for (int mf = 0; mf < 2; ++mf)
        af[mf] = *(const bf16x8*)&As[MO + mf * 16 + x][ks * 32 + g * 8];
      #pragma unroll
      for (int nf = 0; nf < 6; ++nf)
        bfr[nf] = *(const bf16x8*)&Bs[NO + nf * 16 + x][ks * 32 + g * 8];
      #pragma unroll
      for (int mf = 0; mf < 2; ++mf)
        #pragma unroll
        for (int nf = 0; nf < 6; ++nf)
          acc[mf][nf] = __builtin_amdgcn_mfma_f32_16x16x32_bf16(af[mf], bfr[nf], acc[mf][nf], 0, 0, 0);
    }
  }

  #pragma unroll
  for (int nf = 0; nf < 6; ++nf) {
    const int n = NO + nf * 16;
    const int m = n >> 6;
    const float* bias = (m == 0) ? bq : (m == 1) ? bk : bv;
    __bf16* out = (m == 0) ? Q : (m == 1) ? K : V;
    const float sc = (m == 0) ? QSCALE : 1.0f;
    const int nn = (n & 63) + x;
    const float bval = bias[head64 + nn];
    #pragma unroll
    for (int mf = 0; mf < 2; ++mf)
      #pragma unroll
      for (int r = 0; r < 4; ++r) {
        int srow = qt * 64 + MO + mf * 16 + 4 * g + r;
        float val = (acc[mf][nf][r] + bval) * sc;
        out[((size_t)ba * S_ + srow) * DA_ + nn] = (__bf16)val;
      }
  }
}

// ---------------- kernel 4: flash attention, bf16 MFMA, 128-row tile + KV-split ----------------
// grid (S/128=16, B*A=32, 2 KV-halves) = 1024 blocks (4/CU), block 256
// (4 waves, 32 Q-rows each = 2 M-frags). Halves DS reads per MFMA vs the
// 64-row tile (kf/vf serve 2 mf) and halves K/V staging+fetch (half as many
// blocks cover the same KV). Fixed-reference softmax (r11) -> partials
// additive; f32 O-partials + l-partials merged by k_combine. Async reg
// double-buffer staging (r8); V granule-XOR swizzle (r6/r7); Ps overlays Qs.
// LDS = 18.4K (Q/P) + 8K (K) + 8K (V) = 34.8 KB -> 4 blocks/CU.
__global__ __launch_bounds__(256, 4) void k_attn_mfma(const __bf16* __restrict__ Qg,
                                                      const __bf16* __restrict__ Kg,
                                                      const __bf16* __restrict__ Vg,
                                                      float* __restrict__ Opart,
                                                      float* __restrict__ lpart) {
  __shared__ unsigned short QPs[128 * 72];  // Q stage (row*64) then P (row*72)
  __shared__ unsigned short Ks[64 * 64];
  __shared__ unsigned short Vt[64 * 64];    // [da][kv], granule-XOR swizzled

  const int qt = blockIdx.x, ba = blockIdx.y, z = blockIdx.z;
  const int t = threadIdx.x;
  const int w = t >> 6, l = t & 63, x = l & 15, g = l >> 4;

  const unsigned short* Qgu = (const unsigned short*)Qg;
  const unsigned short* Kgu = (const unsigned short*)Kg;
  const unsigned short* Vgu = (const unsigned short*)Vg;

  const size_t kvbase = (size_t)ba * S_ * DA_;
  const int klo = z * 16, khi = klo + 16;

  // staging address components (loop-invariant)
  const int krow = t >> 3, kch = t & 7;
  const int kvp = t >> 3, dab = (t & 7) * 8;
  const int gr = kvp >> 2, wsel = kvp & 3;

  // ---- prologue: issue K/V loads for tile klo ----
  u16x8 kreg0, kreg1, vreg0, vreg1;
  kreg0 = *(const u16x8*)(Kgu + kvbase + (size_t)(klo * 64 + krow) * 64 + kch * 8);
  kreg1 = *(const u16x8*)(Kgu + kvbase + (size_t)(klo * 64 + krow + 32) * 64 + kch * 8);
  vreg0 = *(const u16x8*)(Vgu + kvbase + (size_t)(klo * 64 + 2 * kvp) * 64 + dab);
  vreg1 = *(const u16x8*)(Vgu + kvbase + (size_t)(klo * 64 + 2 * kvp + 1) * 64 + dab);

  // ---- stage Q tile (128 x 64) into QPs, chunk-XOR swizzle ----
  {
    const size_t qbase = ((size_t)ba * S_ + (size_t)qt * 128) * DA_;
    #pragma unroll
    for (int i = 0; i < 4; ++i) {
      int row = (t >> 3) + 32 * i;
      int ch = t & 7;
      u16x8 v = *(const u16x8*)(Qgu + qbase + (size_t)row * 64 + ch * 8);
      *(u16x8*)&QPs[row * 64 + ((ch ^ (row & 7)) << 3)] = v;
    }
  }
  __syncthreads();

  // ---- hoist Q fragments: wave w owns rows w*32 .. w*32+31 (2 mf) ----
  bf16x8 qf[2][2];
  #pragma unroll
  for (int mf = 0; mf < 2; ++mf)
    #pragma unroll
    for (int ks = 0; ks < 2; ++ks) {
      int row = w * 32 + mf * 16 + x;
      int ch = (g + 4 * ks) ^ (row & 7);
      qf[mf][ks] = *(const bf16x8*)&QPs[row * 64 + (ch << 3)];
    }

  f32x4 o_[2][4];
  float l_[2][4];
  #pragma unroll
  for (int mf = 0; mf < 2; ++mf) {
    #pragma unroll
    for (int r = 0; r < 4; ++r) l_[mf][r] = 0.f;
    #pragma unroll
    for (int nf = 0; nf < 4; ++nf) o_[mf][nf] = (f32x4){0.f, 0.f, 0.f, 0.f};
  }

  for (int kt = klo; kt < khi; ++kt) {
    __syncthreads();  // prior reads (incl. Q hoist on iter0) done
    *(u16x8*)&Ks[krow * 64 + ((kch ^ (krow & 7)) << 3)] = kreg0;
    {
      int row1 = krow + 32;
      *(u16x8*)&Ks[row1 * 64 + ((kch ^ (row1 & 7)) << 3)] = kreg1;
    }
    #pragma unroll
    for (int j = 0; j < 8; ++j) {
      int row = dab + j;
      int key = ((row >> 3) ^ row) & 7;
      unsigned int u = (unsigned int)vreg0[j] | ((unsigned int)vreg1[j] << 16);
      *(unsigned int*)&Vt[row * 64 + ((gr ^ key) << 3) + wsel * 2] = u;
    }
    __syncthreads();

    // ---- issue async loads for tile kt+1 ----
    {
      int ktn = (kt + 1 < khi) ? kt + 1 : kt;
      kreg0 = *(const u16x8*)(Kgu + kvbase + (size_t)(ktn * 64 + krow) * 64 + kch * 8);
      kreg1 = *(const u16x8*)(Kgu + kvbase + (size_t)(ktn * 64 + krow + 32) * 64 + kch * 8);
      vreg0 = *(const u16x8*)(Vgu + kvbase + (size_t)(ktn * 64 + 2 * kvp) * 64 + dab);
      vreg1 = *(const u16x8*)(Vgu + kvbase + (size_t)(ktn * 64 + 2 * kvp + 1) * 64 + dab);
    }

    // ---- QK^T (exp2 domain), 2 M-frags per kf read ----
    f32x4 s_[2][4];
    #pragma unroll
    for (int mf = 0; mf < 2; ++mf)
      #pragma unroll
      for (int nf = 0; nf < 4; ++nf) s_[mf][nf] = (f32x4){0.f, 0.f, 0.f, 0.f};
    #pragma unroll
    for (int ks = 0; ks < 2; ++ks) {
      bf16x8 kf[4];
      #pragma unroll
      for (int nf = 0; nf < 4; ++nf) {
        int kvrow = nf * 16 + x;
        int ch = (g + 4 * ks) ^ (kvrow & 7);
        kf[nf] = *(const bf16x8*)&Ks[kvrow * 64 + (ch << 3)];
      }
      #pragma unroll
      for (int mf = 0; mf < 2; ++mf)
        #pragma unroll
        for (int nf = 0; nf < 4; ++nf)
          s_[mf][nf] = __builtin_amdgcn_mfma_f32_16x16x32_bf16(qf[mf][ks], kf[nf], s_[mf][nf], 0, 0, 0);
    }

    // ---- softmax numerator, fixed reference ----
    #pragma unroll
    for (int mf = 0; mf < 2; ++mf)
      #pragma unroll
      for (int r = 0; r < 4; ++r) {
        float rs = 0.f;
        #pragma unroll
        for (int nf = 0; nf < 4; ++nf) {
          float p = exp2f(s_[mf][nf][r] - MREF);
          s_[mf][nf][r] = p;
          rs += p;
        }
        l_[mf][r] += rs;
      }

    // ---- P -> LDS (wave-local rows in QPs) ----
    #pragma unroll
    for (int mf = 0; mf < 2; ++mf)
      #pragma unroll
      for (int nf = 0; nf < 4; ++nf)
        #pragma unroll
        for (int r = 0; r < 4; ++r) {
          int row = w * 32 + mf * 16 + 4 * g + r;
          int col = nf * 16 + x;
          __bf16 pb = (__bf16)s_[mf][nf][r];
          QPs[row * 72 + col] = __builtin_bit_cast(unsigned short, pb);
        }

    // ---- PV: O += P @ V, 2 M-frags per vf read ----
    #pragma unroll
    for (int ks = 0; ks < 2; ++ks) {
      bf16x8 pf[2];
      #pragma unroll
      for (int mf = 0; mf < 2; ++mf)
        pf[mf] = *(const bf16x8*)&QPs[(w * 32 + mf * 16 + x) * 72 + (g * 8 + ks * 32)];
      bf16x8 vf[4];
      #pragma unroll
      for (int nf = 0; nf < 4; ++nf) {
        int darow = nf * 16 + x;
        int key = ((darow >> 3) ^ darow) & 7;
        vf[nf] = *(const bf16x8*)&Vt[darow * 64 + (((g + 4 * ks) ^ key) << 3)];
      }
      #pragma unroll
      for (int mf = 0; mf < 2; ++mf)
        #pragma unroll
        for (int nf = 0; nf < 4; ++nf)
          o_[mf][nf] = __builtin_amdgcn_mfma_f32_16x16x32_bf16(pf[mf], vf[nf], o_[mf][nf], 0, 0, 0);
    }
  }

  // ---- epilogue: write f32 O-partials + per-row l-partials ----
  float* Op = Opart + (size_t)z * ((size_t)B_ * A_ * S_ * DA_);
  #pragma unroll
  for (int mf = 0; mf < 2; ++mf) {
    #pragma unroll
    for (int r = 0; r < 4; ++r) {
      float lr = l_[mf][r];
      lr += __shfl_xor(lr, 1);
      lr += __shfl_xor(lr, 2);
      lr += __shfl_xor(lr, 4);
      lr += __shfl_xor(lr, 8);
      if (x == 0) {
        int row = qt * 128 + w * 32 + mf * 16 + 4 * g + r;
        lpart[(size_t)z * (B_ * A_ * S_) + (size_t)ba * S_ + row] = lr;
      }
    }
    #pragma unroll
    for (int nf = 0; nf < 4; ++nf)
      #pragma unroll
      for (int r = 0; r < 4; ++r) {
        int row = qt * 128 + w * 32 + mf * 16 + 4 * g + r;
        int col = nf * 16 + x;
        Op[((size_t)ba * S_ + row) * DA_ + col] = o_[mf][nf][r];
      }
  }
}

// ---------------- kernel 4b: combine KV-split partials -> bf16 Ofin ----------------
__global__ __launch_bounds__(256) void k_combine(const float* __restrict__ Opart,
                                                 const float* __restrict__ lpart,
                                                 const float* __restrict__ dist,
                                                 __bf16* __restrict__ Ofin) {
  const size_t e = ((size_t)blockIdx.x * 256 + threadIdx.x) * 8;
  const int row = (int)(e >> 6);          // ba*S + s
  const int col = (int)(e & 63);
  const int ba = row >> 11, s = row & (S_ - 1);
  const int b = ba >> 2, a = ba & 3;
  const float* Op1 = Opart + (size_t)B_ * A_ * S_ * DA_;
  f32x4 p00 = *(const f32x4*)(Opart + (size_t)row * DA_ + col);
  f32x4 p01 = *(const f32x4*)(Opart + (size_t)row * DA_ + col + 4);
  f32x4 p10 = *(const f32x4*)(Op1 + (size_t)row * DA_ + col);
  f32x4 p11 = *(const f32x4*)(Op1 + (size_t)row * DA_ + col + 4);
  const float ls = lpart[row] + lpart[B_ * A_ * S_ + row];
  const float sc = dist[ba] / ls;
  bf16x8 o;
  #pragma unroll
  for (int j = 0; j < 4; ++j) o[j] = (__bf16)((p00[j] + p10[j]) * sc);
  #pragma unroll
  for (int j = 0; j < 4; ++j) o[4 + j] = (__bf16)((p01[j] + p11[j]) * sc);
  *(bf16x8*)(Ofin + ((size_t)(b * S_ + s)) * (A_ * DA_) + a * DA_ + col) = o;
}

// ---------------- kernel 5: output projection, bf16 MFMA ----------------
__global__ __launch_bounds__(256) void k_oproj_mfma(const __bf16* __restrict__ Of,
                                                    const __bf16* __restrict__ WoT,
                                                    const float* __restrict__ bo,
                                                    float* __restrict__ Z) {
  __shared__ unsigned short As[128][72];
  __shared__ unsigned short Bs[128][72];
  const int nt = blockIdx.x, mt = blockIdx.y;
  const int t = threadIdx.x;
  const int w = t >> 6, l = t & 63, x = l & 15, g = l >> 4;
  const int MO = (w >> 1) * 64, NO = (w & 1) * 64;

  const unsigned short* Ofu = (const unsigned short*)Of;
  const unsigned short* Wu  = (const unsigned short*)WoT;

  f32x4 acc[4][4];
  #pragma unroll
  for (int mf = 0; mf < 4; ++mf)
    #pragma unroll
    for (int nf = 0; nf < 4; ++nf) acc[mf][nf] = (f32x4){0.f, 0.f, 0.f, 0.f};

  for (int k0 = 0; k0 < A_ * DA_; k0 += 64) {
    #pragma unroll
    for (int i = 0; i < 4; ++i) {
      int id = t + 256 * i;
      int row = id >> 3, ch = id & 7;
      u16x8 v = *(const u16x8*)(Ofu + ((size_t)(mt * 128 + row)) * (A_ * DA_) + k0 + ch * 8);
      *(u16x8*)&As[row][ch * 8] = v;
    }
    #pragma unroll
    for (int i = 0; i < 4; ++i) {
      int id = t + 256 * i;
      int row = id >> 3, ch = id & 7;
      u16x8 v = *(const u16x8*)(Wu + ((size_t)(nt * 128 + row)) * (A_ * DA_) + k0 + ch * 8);
      *(u16x8*)&Bs[row][ch * 8] = v;
    }
    __syncthreads();
    #pragma unroll
    for (int ks = 0; ks < 2; ++ks) {
      bf16x8 af[4], bfr[4];
      #pragma unroll
      for (int mf = 0; mf < 4; ++mf)
        af[mf] = *(const bf16x8*)&As[MO + mf * 16 + x][ks * 32 + g * 8];
      #pragma unroll
      for (int nf = 0; nf < 4; ++nf)
        bfr[nf] = *(const bf16x8*)&Bs[NO + nf * 16 + x][ks * 32 + g * 8];
      #pragma unroll
      for (int mf = 0; mf < 4; ++mf)
        #pragma unroll
        for (int nf = 0; nf < 4; ++nf)
          acc[mf][nf] = __builtin_amdgcn_mfma_f32_16x16x32_bf16(af[mf], bfr[nf], acc[mf][nf], 0, 0, 0);
    }
    __syncthreads();
  }

  #pragma unroll
  for (int nf = 0; nf < 4; ++nf) {
    const int n = nt * 128 + NO + nf * 16 + x;
    const float bval = bo[n];
    #pragma unroll
    for (int mf = 0; mf < 4; ++mf)
      #pragma unroll
      for (int r = 0; r < 4; ++r) {
        int row = mt * 128 + MO + mf * 16 + 4 * g + r;
        Z[(size_t)row * D_ + n] = acc[mf][nf][r] + bval;
      }
  }
}

extern "C" void kernel_launch(void* const* d_in, const int* in_sizes, int n_in,
                              void* d_out, int out_size, void* d_ws, size_t ws_size,
                              hipStream_t stream) {
  const float* x     = (const float*)d_in[0];
  const float* Wq    = (const float*)d_in[1];
  const float* bq    = (const float*)d_in[2];
  const float* Wk    = (const float*)d_in[3];
  const float* bk    = (const float*)d_in[4];
  const float* Wv    = (const float*)d_in[5];
  const float* bv    = (const float*)d_in[6];
  const float* Wr    = (const float*)d_in[7];
  const float* br    = (const float*)d_in[8];
  const float* gamma = (const float*)d_in[9];
  const float* beta  = (const float*)d_in[10];
  const float* Wo    = (const float*)d_in[11];
  const float* bo    = (const float*)d_in[12];
  float* Z = (float*)d_out;

  char* ws = (char*)d_ws;
  float*  partial = (float*)(ws + OFF_PARTIAL);
  float*  lpart   = (float*)(ws + OFF_LPART);
  int*    idx     = (int*)(ws + OFF_IDX);
  float*  dist    = (float*)(ws + OFF_DIST);
  __bf16* WoT     = (__bf16*)(ws + OFF_WOT);
  __bf16* xb      = (__bf16*)(ws + OFF_XB);
  float*  Opart   = (float*)(ws + OFF_OPART);
  __bf16* Wt      = (__bf16*)(ws + OFF_WT);
  __bf16* Q       = (__bf16*)(ws + OFF_Q);
  __bf16* Ofin    = (__bf16*)(ws + OFF_OFIN);
  __bf16* K       = (__bf16*)(ws + OFF_K);
  __bf16* V       = (__bf16*)(ws + OFF_V);

  k_partial<<<dim3(32, B_), 256, 0, stream>>>(x, partial, xb);
  k_wt<<<dim3(16, 16, 3), 256, 0, stream>>>(Wq, Wk, Wv, Wt);
  k_wto<<<dim3(16, 4), 256, 0, stream>>>(Wo, WoT);
  k_stats<<<B_, 256, 0, stream>>>(partial, Wr, br, gamma, beta, idx, dist);
  k_qkv_mfma<<<dim3(S_ / 64, B_ * A_), 256, 0, stream>>>(xb, Wt, bq, bk, bv, idx, Q, K, V);
  k_attn_mfma<<<dim3(S_ / 128, B_ * A_, 2), 256, 0, stream>>>(Q, K, V, Opart, lpart);
  k_combine<<<2048, 256, 0, stream>>>(Opart, lpart, dist, Ofin);
  k_oproj_mfma<<<dim3(D_ / 128, (B_ * S_) / 128), 256, 0, stream>>>(Ofin, WoT, bo, Z);
}

// Round 14
// 191.905 us; speedup vs baseline: 1.1267x; 1.1267x over previous
//
#include <hip/hip_runtime.h>
#include <math.h>

#define B_ 8
#define S_ 2048
#define D_ 1024
#define H_ 16
#define A_ 4
#define DA_ 64
#define LN_EPS 1e-5f
// 0.125 * log2(e): Q pre-scale so softmax runs in exp2 domain
#define QSCALE 0.1803368801111204f
// fixed softmax reference (log2 units), folded into the QK accumulator init
#define MREF 20.0f

typedef __bf16 bf16x8 __attribute__((ext_vector_type(8)));
typedef __bf16 bf16x4 __attribute__((ext_vector_type(4)));
typedef float f32x4 __attribute__((ext_vector_type(4)));
typedef unsigned short u16x8 __attribute__((ext_vector_type(8)));

// ---------------- workspace layout (bytes) ----------------
// 0      : partial 1MB (k_partial->k_stats), then lpart 512KB (attn->combine)
// 1MB    : idx ; 1MB+1K: dist ; 1.5MB: WoT bf16 512KB
// 2MB    : xb bf16 32MB (dead after qkv) -> Opart f32 2x16MB (attn->combine)
// 34MB   : Wt bf16 6MB
// 40MB   : Q bf16 8MB (dead after attn) -> Ofin bf16 8MB (combine->oproj)
// 48MB   : K ; 56MB : Vt (bf16, TRANSPOSED [ba][da][s]).  total 64MB.
static const size_t OFF_PARTIAL = 0;
static const size_t OFF_LPART   = 0;
static const size_t OFF_IDX     = (size_t)1 << 20;
static const size_t OFF_DIST    = ((size_t)1 << 20) + 1024;
static const size_t OFF_WOT     = ((size_t)1 << 20) + ((size_t)1 << 19);
static const size_t OFF_XB      = (size_t)2 << 20;
static const size_t OFF_OPART   = OFF_XB;
static const size_t OFF_WT      = (size_t)34 << 20;
static const size_t OFF_Q       = (size_t)40 << 20;
static const size_t OFF_OFIN    = OFF_Q;
static const size_t OFF_K       = (size_t)48 << 20;
static const size_t OFF_V       = (size_t)56 << 20;

// ---------------- kernel 1: column-sum partial over S + bf16 convert ----------------
__global__ __launch_bounds__(256) void k_partial(const float* __restrict__ x,
                                                 float* __restrict__ partial,
                                                 __bf16* __restrict__ xb) {
  const int c = blockIdx.x, b = blockIdx.y, t = threadIdx.x;
  const size_t base = ((size_t)b * S_ + (size_t)c * 64) * D_;
  f32x4 acc = {0.f, 0.f, 0.f, 0.f};
  for (int s = 0; s < 64; ++s) {
    f32x4 v = *(const f32x4*)(x + base + (size_t)s * D_ + 4 * t);
    acc += v;
    bf16x4 o;
    #pragma unroll
    for (int j = 0; j < 4; ++j) o[j] = (__bf16)v[j];
    *(bf16x4*)(xb + base + (size_t)s * D_ + 4 * t) = o;
  }
  *(f32x4*)(partial + ((size_t)b * 32 + c) * D_ + 4 * t) = acc;
}

// ---------------- kernel 1b: transpose QKV weights to bf16 [m][n][k] ----------------
__global__ __launch_bounds__(256) void k_wt(const float* __restrict__ Wq,
                                            const float* __restrict__ Wk,
                                            const float* __restrict__ Wv,
                                            __bf16* __restrict__ Wt) {
  __shared__ float tsh[64][65];
  const int n0 = blockIdx.x * 64, k0 = blockIdx.y * 64, z = blockIdx.z;
  const float* W = (z == 0) ? Wq : (z == 1) ? Wk : Wv;
  const int t = threadIdx.x;
  #pragma unroll
  for (int i = 0; i < 4; ++i) {
    int r = i * 16 + (t >> 4), c = (t & 15) * 4;
    f32x4 v = *(const f32x4*)(W + (size_t)(k0 + r) * (H_ * DA_) + n0 + c);
    tsh[r][c + 0] = v[0]; tsh[r][c + 1] = v[1]; tsh[r][c + 2] = v[2]; tsh[r][c + 3] = v[3];
  }
  __syncthreads();
  #pragma unroll
  for (int i = 0; i < 4; ++i) {
    int n = i * 16 + (t >> 4), kc = (t & 15) * 4;
    bf16x4 o;
    #pragma unroll
    for (int j = 0; j < 4; ++j) o[j] = (__bf16)tsh[kc + j][n];
    *(bf16x4*)(Wt + (size_t)z * 1048576 + (size_t)(n0 + n) * 1024 + k0 + kc) = o;
  }
}

// ---------------- kernel 1c: transpose Wo [256][1024] -> WoT bf16 [1024][256] ----------------
__global__ __launch_bounds__(256) void k_wto(const float* __restrict__ Wo,
                                             __bf16* __restrict__ WoT) {
  __shared__ float tsh[64][65];
  const int n0 = blockIdx.x * 64, k0 = blockIdx.y * 64;
  const int t = threadIdx.x;
  #pragma unroll
  for (int i = 0; i < 4; ++i) {
    int r = i * 16 + (t >> 4), c = (t & 15) * 4;
    f32x4 v = *(const f32x4*)(Wo + (size_t)(k0 + r) * D_ + n0 + c);
    tsh[r][c + 0] = v[0]; tsh[r][c + 1] = v[1]; tsh[r][c + 2] = v[2]; tsh[r][c + 3] = v[3];
  }
  __syncthreads();
  #pragma unroll
  for (int i = 0; i < 4; ++i) {
    int n = i * 16 + (t >> 4), kc = (t & 15) * 4;
    bf16x4 o;
    #pragma unroll
    for (int j = 0; j < 4; ++j) o[j] = (__bf16)tsh[kc + j][n];
    *(bf16x4*)(WoT + (size_t)(n0 + n) * (A_ * DA_) + k0 + kc) = o;
  }
}

// ---------------- kernel 2: xbar -> r -> LN -> softmax -> top4 ----------------
__global__ __launch_bounds__(256) void k_stats(const float* __restrict__ partial,
                                               const float* __restrict__ Wr,
                                               const float* __restrict__ br,
                                               const float* __restrict__ gamma,
                                               const float* __restrict__ beta,
                                               int* __restrict__ idx_out,
                                               float* __restrict__ dist_out) {
  __shared__ float xbar[D_];
  __shared__ float rsh[H_];
  const int b = blockIdx.x, t = threadIdx.x;
  #pragma unroll
  for (int j = 0; j < 4; ++j) {
    int d = j * 256 + t;
    float s = 0.f;
    for (int c = 0; c < 32; ++c) s += partial[((size_t)b * 32 + c) * D_ + d];
    xbar[d] = s * (1.0f / S_);
  }
  __syncthreads();
  const int w = t >> 6, lane = t & 63;
  #pragma unroll
  for (int i = 0; i < 4; ++i) {
    int h = w * 4 + i;
    float s = 0.f;
    #pragma unroll
    for (int j = 0; j < 16; ++j) {
      int d = j * 64 + lane;
      s += xbar[d] * Wr[d * H_ + h];
    }
    for (int off = 32; off; off >>= 1) s += __shfl_down(s, off);
    if (lane == 0) rsh[h] = s + br[h];
  }
  __syncthreads();
  if (t == 0) {
    float r[H_];
    float mu = 0.f;
    for (int h = 0; h < H_; ++h) { r[h] = rsh[h]; mu += r[h]; }
    mu *= (1.0f / H_);
    float var = 0.f;
    for (int h = 0; h < H_; ++h) { float d = r[h] - mu; var += d * d; }
    var *= (1.0f / H_);
    float inv = rsqrtf(var + LN_EPS);
    float rn[H_], ex[H_];
    float mx = -1e30f;
    for (int h = 0; h < H_; ++h) {
      rn[h] = (r[h] - mu) * inv * gamma[h] + beta[h];
      mx = fmaxf(mx, rn[h]);
    }
    float sum = 0.f;
    for (int h = 0; h < H_; ++h) { ex[h] = expf(rn[h] - mx); sum += ex[h]; }
    int sel[A_];
    bool used[H_] = {false};
    for (int a = 0; a < A_; ++a) {
      int best = 0; float bv = -1.f;
      for (int h = 0; h < H_; ++h)
        if (!used[h] && ex[h] > bv) { bv = ex[h]; best = h; }
      used[best] = true; sel[a] = best;
    }
    for (int i = 0; i < A_; ++i)
      for (int j = i + 1; j < A_; ++j)
        if (sel[j] < sel[i]) { int tmp = sel[i]; sel[i] = sel[j]; sel[j] = tmp; }
    float invsum = 1.0f / sum;
    for (int a = 0; a < A_; ++a) {
      idx_out[b * A_ + a] = sel[a];
      dist_out[b * A_ + a] = ex[sel[a]] * invsum;
    }
  }
}

// ---------------- kernel 3: QKV projection, bf16 MFMA ----------------
// grid (S/64=32, B*A=32) = 1024 blocks (4/CU), block 256 (4 waves).
// Tile 64(M) x 192(N), BK=64. Wave owns 32x96 (2x6 frags). Async reg
// double-buffer staging. Q pre-scaled by QSCALE. V written TRANSPOSED
// (Vt[ba][da][s]) via an LDS bounce through the dead As buffer, so the
// attention kernel can stage V exactly like K (chunk-XOR, b128).
__global__ __launch_bounds__(256) void k_qkv_mfma(const __bf16* __restrict__ xb,
                                                  const __bf16* __restrict__ Wt,
                                                  const float* __restrict__ bq,
                                                  const float* __restrict__ bk,
                                                  const float* __restrict__ bv,
                                                  const int* __restrict__ idx,
                                                  __bf16* __restrict__ Q,
                                                  __bf16* __restrict__ K,
                                                  __bf16* __restrict__ Vt_g) {
  __shared__ unsigned short As[64][72];
  __shared__ unsigned short Bs[192][72];
  const int qt = blockIdx.x, ba = blockIdx.y;
  const int b = ba >> 2;
  const int head64 = idx[ba] * 64;
  const int t = threadIdx.x;
  const int w = t >> 6, l = t & 63, x = l & 15, g = l >> 4;
  const int MO = (w >> 1) * 32, NO = (w & 1) * 96;

  const unsigned short* xbu = (const unsigned short*)xb;
  const unsigned short* Wtu = (const unsigned short*)Wt;
  const size_t xbase = ((size_t)b * S_ + (size_t)qt * 64) * D_;

  u16x8 areg[2], breg[6];
  #pragma unroll
  for (int i = 0; i < 2; ++i) {
    int id = t + 256 * i, row = id >> 3, ch = id & 7;
    areg[i] = *(const u16x8*)(xbu + xbase + (size_t)row * D_ + ch * 8);
  }
  #pragma unroll
  for (int i = 0; i < 6; ++i) {
    int id = t + 256 * i, row = id >> 3, ch = id & 7;
    int m = row >> 6, nn = row & 63;
    breg[i] = *(const u16x8*)(Wtu + (size_t)m * 1048576 +
                              (size_t)(head64 + nn) * 1024 + ch * 8);
  }

  f32x4 acc[2][6];
  #pragma unroll
  for (int mf = 0; mf < 2; ++mf)
    #pragma unroll
    for (int nf = 0; nf < 6; ++nf) acc[mf][nf] = (f32x4){0.f, 0.f, 0.f, 0.f};

  for (int k0 = 0; k0 < D_; k0 += 64) {
    __syncthreads();
    #pragma unroll
    for (int i = 0; i < 2; ++i) {
      int id = t + 256 * i, row = id >> 3, ch = id & 7;
      *(u16x8*)&As[row][ch * 8] = areg[i];
    }
    #pragma unroll
    for (int i = 0; i < 6; ++i) {
      int id = t + 256 * i, row = id >> 3, ch = id & 7;
      *(u16x8*)&Bs[row][ch * 8] = breg[i];
    }
    __syncthreads();
    {
      int kn = (k0 + 64 < D_) ? k0 + 64 : k0;
      #pragma unroll
      for (int i = 0; i < 2; ++i) {
        int id = t + 256 * i, row = id >> 3, ch = id & 7;
        areg[i] = *(const u16x8*)(xbu + xbase + (size_t)row * D_ + kn + ch * 8);
      }
      #pragma unroll
      for (int i = 0; i < 6; ++i) {
        int id = t + 256 * i, row = id >> 3, ch = id & 7;
        int m = row >> 6, nn = row & 63;
        breg[i] = *(const u16x8*)(Wtu + (size_t)m * 1048576 +
                                  (size_t)(head64 + nn) * 1024 + kn + ch * 8);
      }
    }
    #pragma unroll
    for (int ks = 0; ks < 2; ++ks) {
      bf16x8 af[2], bfr[6];
      #pragma unroll
      for (int mf = 0; mf < 2; ++mf)
        af[mf] = *(const bf16x8*)&As[MO + mf * 16 + x][ks * 32 + g * 8];
      #pragma unroll
      for (int nf = 0; nf < 6; ++nf)
        bfr[nf] = *(const bf16x8*)&Bs[NO + nf * 16 + x][ks * 32 + g * 8];
      #pragma unroll
      for (int mf = 0; mf < 2; ++mf)
        #pragma unroll
        for (int nf = 0; nf < 6; ++nf)
          acc[mf][nf] = __builtin_amdgcn_mfma_f32_16x16x32_bf16(af[mf], bfr[nf], acc[mf][nf], 0, 0, 0);
    }
  }

  // ---- epilogue: Q and K direct (row-major); V via LDS bounce, transposed ----
  #pragma unroll
  for (int nf = 0; nf < 6; ++nf) {
    const int n = NO + nf * 16;
    const int m = n >> 6;
    if (m == 2) continue;                 // V handled by the bounce below
    const float* bias = (m == 0) ? bq : bk;
    __bf16* out = (m == 0) ? Q : K;
    const float sc = (m == 0) ? QSCALE : 1.0f;
    const int nn = (n & 63) + x;
    const float bval = bias[head64 + nn];
    #pragma unroll
    for (int mf = 0; mf < 2; ++mf)
      #pragma unroll
      for (int r = 0; r < 4; ++r) {
        int srow = qt * 64 + MO + mf * 16 + 4 * g + r;
        float val = (acc[mf][nf][r] + bval) * sc;
        out[((size_t)ba * S_ + srow) * DA_ + nn] = (__bf16)val;
      }
  }

  __syncthreads();                        // As dead (main loop done)
  if (w & 1) {                            // waves 1,3 own V (nf=2..5)
    #pragma unroll
    for (int nf = 2; nf < 6; ++nf) {
      const int da = (nf - 2) * 16 + x;
      const float bval = bv[head64 + da];
      #pragma unroll
      for (int mf = 0; mf < 2; ++mf)
        #pragma unroll
        for (int r = 0; r < 4; ++r) {
          int ls = MO + mf * 16 + 4 * g + r;   // local s-row 0..63
          __bf16 vb = (__bf16)(acc[mf][nf][r] + bval);
          As[da][ls] = __builtin_bit_cast(unsigned short, vb);
        }
    }
  }
  __syncthreads();
  {
    unsigned short* Vtu = (unsigned short*)Vt_g;
    const int vrow = t >> 3, vch = t & 7;
    u16x8 v0 = *(const u16x8*)&As[vrow][vch * 8];
    u16x8 v1 = *(const u16x8*)&As[vrow + 32][vch * 8];
    const size_t vb0 = (size_t)ba * DA_ * S_;
    *(u16x8*)(Vtu + vb0 + (size_t)vrow * S_ + qt * 64 + vch * 8) = v0;
    *(u16x8*)(Vtu + vb0 + (size_t)(vrow + 32) * S_ + qt * 64 + vch * 8) = v1;
  }
}

// ---------------- kernel 4: flash attention, bf16 MFMA, KV-split x2 ----------------
// grid (S/64=32, B*A=32, 2 KV-halves) = 2048 blocks, block 256 (4 waves,
// 16 Q-rows each). r12-verified skeleton. V now staged EXACTLY like K
// (global Vt[ba][da][s] rows -> chunk-XOR b128 LDS writes) — replaces the
// 8x b32 packed transpose writes. Fixed-reference softmax with -MREF folded
// into the QK accumulator init. Partials additive; k_combine merges.
__global__ __launch_bounds__(256, 4) void k_attn_mfma(const __bf16* __restrict__ Qg,
                                                      const __bf16* __restrict__ Kg,
                                                      const __bf16* __restrict__ Vtg,
                                                      float* __restrict__ Opart,
                                                      float* __restrict__ lpart) {
  __shared__ unsigned short QPs[64 * 72];  // Qs (stage, row*64) then Ps (row*72)
  __shared__ unsigned short Ks[64 * 64];   // chunk-XOR swizzled
  __shared__ unsigned short Vt[64 * 64];   // [da][kv], chunk-XOR swizzled

  const int qt = blockIdx.x, ba = blockIdx.y, z = blockIdx.z;
  const int t = threadIdx.x;
  const int w = t >> 6, l = t & 63, x = l & 15, g = l >> 4;

  const unsigned short* Qgu = (const unsigned short*)Qg;
  const unsigned short* Kgu = (const unsigned short*)Kg;
  const unsigned short* Vgu = (const unsigned short*)Vtg;

  const size_t kvbase = (size_t)ba * S_ * DA_;   // K base (row-major [s][da])
  const size_t vbase  = (size_t)ba * DA_ * S_;   // Vt base ([da][s])
  const int klo = z * 16, khi = klo + 16;

  // staging address components (loop-invariant); V uses the same (row, ch)
  const int krow = t >> 3, kch = t & 7;

  // ---- prologue: issue K/V loads for tile klo ----
  u16x8 kreg0, kreg1, vreg0, vreg1;
  kreg0 = *(const u16x8*)(Kgu + kvbase + (size_t)(klo * 64 + krow) * 64 + kch * 8);
  kreg1 = *(const u16x8*)(Kgu + kvbase + (size_t)(klo * 64 + krow + 32) * 64 + kch * 8);
  vreg0 = *(const u16x8*)(Vgu + vbase + (size_t)krow * S_ + klo * 64 + kch * 8);
  vreg1 = *(const u16x8*)(Vgu + vbase + (size_t)(krow + 32) * S_ + klo * 64 + kch * 8);

  // ---- stage Q tile (64 x 64) into QPs, chunk-XOR swizzle ----
  {
    const size_t qbase = ((size_t)ba * S_ + (size_t)qt * 64) * DA_;
    #pragma unroll
    for (int i = 0; i < 2; ++i) {
      int row = (t >> 3) + 32 * i;
      int ch = t & 7;
      u16x8 v = *(const u16x8*)(Qgu + qbase + (size_t)row * 64 + ch * 8);
      *(u16x8*)&QPs[row * 64 + ((ch ^ (row & 7)) << 3)] = v;
    }
  }
  __syncthreads();

  // ---- hoist Q fragments: wave w owns rows w*16..w*16+15 ----
  bf16x8 qf[2];
  #pragma unroll
  for (int ks = 0; ks < 2; ++ks) {
    int row = w * 16 + x;
    int ch = (g + 4 * ks) ^ (row & 7);
    qf[ks] = *(const bf16x8*)&QPs[row * 64 + (ch << 3)];
  }

  f32x4 o_[4];
  float l_[4];
  #pragma unroll
  for (int r = 0; r < 4; ++r) l_[r] = 0.f;
  #pragma unroll
  for (int nf = 0; nf < 4; ++nf) o_[nf] = (f32x4){0.f, 0.f, 0.f, 0.f};

  for (int kt = klo; kt < khi; ++kt) {
    __syncthreads();  // prior reads (incl. Q hoist on iter0) done
    // ---- write staged regs -> LDS, chunk-XOR (K and V identical) ----
    *(u16x8*)&Ks[krow * 64 + ((kch ^ (krow & 7)) << 3)] = kreg0;
    *(u16x8*)&Vt[krow * 64 + ((kch ^ (krow & 7)) << 3)] = vreg0;
    {
      int row1 = krow + 32;
      *(u16x8*)&Ks[row1 * 64 + ((kch ^ (row1 & 7)) << 3)] = kreg1;
      *(u16x8*)&Vt[row1 * 64 + ((kch ^ (row1 & 7)) << 3)] = vreg1;
    }
    __syncthreads();

    // ---- issue async loads for tile kt+1 ----
    {
      int ktn = (kt + 1 < khi) ? kt + 1 : kt;
      kreg0 = *(const u16x8*)(Kgu + kvbase + (size_t)(ktn * 64 + krow) * 64 + kch * 8);
      kreg1 = *(const u16x8*)(Kgu + kvbase + (size_t)(ktn * 64 + krow + 32) * 64 + kch * 8);
      vreg0 = *(const u16x8*)(Vgu + vbase + (size_t)krow * S_ + ktn * 64 + kch * 8);
      vreg1 = *(const u16x8*)(Vgu + vbase + (size_t)(krow + 32) * S_ + ktn * 64 + kch * 8);
    }

    // ---- QK^T (exp2 domain), C-init = -MREF ----
    f32x4 s_[4];
    #pragma unroll
    for (int nf = 0; nf < 4; ++nf) s_[nf] = (f32x4){-MREF, -MREF, -MREF, -MREF};
    #pragma unroll
    for (int ks = 0; ks < 2; ++ks) {
      bf16x8 kf[4];
      #pragma unroll
      for (int nf = 0; nf < 4; ++nf) {
        int kvrow = nf * 16 + x;
        int ch = (g + 4 * ks) ^ (kvrow & 7);
        kf[nf] = *(const bf16x8*)&Ks[kvrow * 64 + (ch << 3)];
      }
      #pragma unroll
      for (int nf = 0; nf < 4; ++nf)
        s_[nf] = __builtin_amdgcn_mfma_f32_16x16x32_bf16(qf[ks], kf[nf], s_[nf], 0, 0, 0);
    }

    // ---- softmax numerator: p = exp2(s) (reference pre-subtracted) ----
    #pragma unroll
    for (int r = 0; r < 4; ++r) {
      float rs = 0.f;
      #pragma unroll
      for (int nf = 0; nf < 4; ++nf) {
        float p = exp2f(s_[nf][r]);
        s_[nf][r] = p;
        rs += p;
      }
      l_[r] += rs;
    }

    // ---- P -> LDS (wave-local rows in QPs) ----
    #pragma unroll
    for (int nf = 0; nf < 4; ++nf)
      #pragma unroll
      for (int r = 0; r < 4; ++r) {
        int row = w * 16 + 4 * g + r;
        int col = nf * 16 + x;
        __bf16 pb = (__bf16)s_[nf][r];
        QPs[row * 72 + col] = __builtin_bit_cast(unsigned short, pb);
      }

    // ---- PV: O += P @ V ----
    #pragma unroll
    for (int ks = 0; ks < 2; ++ks) {
      bf16x8 pf = *(const bf16x8*)&QPs[(w * 16 + x) * 72 + (g * 8 + ks * 32)];
      bf16x8 vf[4];
      #pragma unroll
      for (int nf = 0; nf < 4; ++nf) {
        int darow = nf * 16 + x;
        int ch = (g + 4 * ks) ^ (darow & 7);
        vf[nf] = *(const bf16x8*)&Vt[darow * 64 + (ch << 3)];
      }
      #pragma unroll
      for (int nf = 0; nf < 4; ++nf)
        o_[nf] = __builtin_amdgcn_mfma_f32_16x16x32_bf16(pf, vf[nf], o_[nf], 0, 0, 0);
    }
  }

  // ---- epilogue: write f32 O-partial + per-row l-partial ----
  float* Op = Opart + (size_t)z * ((size_t)B_ * A_ * S_ * DA_);
  #pragma unroll
  for (int r = 0; r < 4; ++r) {
    float lr = l_[r];
    lr += __shfl_xor(lr, 1);
    lr += __shfl_xor(lr, 2);
    lr += __shfl_xor(lr, 4);
    lr += __shfl_xor(lr, 8);
    if (x == 0) {
      int row = qt * 64 + w * 16 + 4 * g + r;
      lpart[(size_t)z * (B_ * A_ * S_) + (size_t)ba * S_ + row] = lr;
    }
  }
  #pragma unroll
  for (int nf = 0; nf < 4; ++nf)
    #pragma unroll
    for (int r = 0; r < 4; ++r) {
      int row = qt * 64 + w * 16 + 4 * g + r;
      int col = nf * 16 + x;
      Op[((size_t)ba * S_ + row) * DA_ + col] = o_[nf][r];
    }
}

// ---------------- kernel 4b: combine KV-split partials -> bf16 Ofin ----------------
__global__ __launch_bounds__(256) void k_combine(const float* __restrict__ Opart,
                                                 const float* __restrict__ lpart,
                                                 const float* __restrict__ dist,
                                                 __bf16* __restrict__ Ofin) {
  const size_t e = ((size_t)blockIdx.x * 256 + threadIdx.x) * 8;
  const int row = (int)(e >> 6);          // ba*S + s
  const int col = (int)(e & 63);
  const int ba = row >> 11, s = row & (S_ - 1);
  const int b = ba >> 2, a = ba & 3;
  const float* Op1 = Opart + (size_t)B_ * A_ * S_ * DA_;
  f32x4 p00 = *(const f32x4*)(Opart + (size_t)row * DA_ + col);
  f32x4 p01 = *(const f32x4*)(Opart + (size_t)row * DA_ + col + 4);
  f32x4 p10 = *(const f32x4*)(Op1 + (size_t)row * DA_ + col);
  f32x4 p11 = *(const f32x4*)(Op1 + (size_t)row * DA_ + col + 4);
  const float ls = lpart[row] + lpart[B_ * A_ * S_ + row];
  const float sc = dist[ba] / ls;
  bf16x8 o;
  #pragma unroll
  for (int j = 0; j < 4; ++j) o[j] = (__bf16)((p00[j] + p10[j]) * sc);
  #pragma unroll
  for (int j = 0; j < 4; ++j) o[4 + j] = (__bf16)((p01[j] + p11[j]) * sc);
  *(bf16x8*)(Ofin + ((size_t)(b * S_ + s)) * (A_ * DA_) + a * DA_ + col) = o;
}

// ---------------- kernel 5: output projection, bf16 MFMA ----------------
__global__ __launch_bounds__(256) void k_oproj_mfma(const __bf16* __restrict__ Of,
                                                    const __bf16* __restrict__ WoT,
                                                    const float* __restrict__ bo,
                                                    float* __restrict__ Z) {
  __shared__ unsigned short As[128][72];
  __shared__ unsigned short Bs[128][72];
  const int nt = blockIdx.x, mt = blockIdx.y;
  const int t = threadIdx.x;
  const int w = t >> 6, l = t & 63, x = l & 15, g = l >> 4;
  const int MO = (w >> 1) * 64, NO = (w & 1) * 64;

  const unsigned short* Ofu = (const unsigned short*)Of;
  const unsigned short* Wu  = (const unsigned short*)WoT;

  f32x4 acc[4][4];
  #pragma unroll
  for (int mf = 0; mf < 4; ++mf)
    #pragma unroll
    for (int nf = 0; nf < 4; ++nf) acc[mf][nf] = (f32x4){0.f, 0.f, 0.f, 0.f};

  for (int k0 = 0; k0 < A_ * DA_; k0 += 64) {
    #pragma unroll
    for (int i = 0; i < 4; ++i) {
      int id = t + 256 * i;
      int row = id >> 3, ch = id & 7;
      u16x8 v = *(const u16x8*)(Ofu + ((size_t)(mt * 128 + row)) * (A_ * DA_) + k0 + ch * 8);
      *(u16x8*)&As[row][ch * 8] = v;
    }
    #pragma unroll
    for (int i = 0; i < 4; ++i) {
      int id = t + 256 * i;
      int row = id >> 3, ch = id & 7;
      u16x8 v = *(const u16x8*)(Wu + ((size_t)(nt * 128 + row)) * (A_ * DA_) + k0 + ch * 8);
      *(u16x8*)&Bs[row][ch * 8] = v;
    }
    __syncthreads();
    #pragma unroll
    for (int ks = 0; ks < 2; ++ks) {
      bf16x8 af[4], bfr[4];
      #pragma unroll
      for (int mf = 0; mf < 4; ++mf)
        af[mf] = *(const bf16x8*)&As[MO + mf * 16 + x][ks * 32 + g * 8];
      #pragma unroll
      for (int nf = 0; nf < 4; ++nf)
        bfr[nf] = *(const bf16x8*)&Bs[NO + nf * 16 + x][ks * 32 + g * 8];
      #pragma unroll
      for (int mf = 0; mf < 4; ++mf)
        #pragma unroll
        for (int nf = 0; nf < 4; ++nf)
          acc[mf][nf] = __builtin_amdgcn_mfma_f32_16x16x32_bf16(af[mf], bfr[nf], acc[mf][nf], 0, 0, 0);
    }
    __syncthreads();
  }

  #pragma unroll
  for (int nf = 0; nf < 4; ++nf) {
    const int n = nt * 128 + NO + nf * 16 + x;
    const float bval = bo[n];
    #pragma unroll
    for (int mf = 0; mf < 4; ++mf)
      #pragma unroll
      for (int r = 0; r < 4; ++r) {
        int row = mt * 128 + MO + mf * 16 + 4 * g + r;
        Z[(size_t)row * D_ + n] = acc[mf][nf][r] + bval;
      }
  }
}

extern "C" void kernel_launch(void* const* d_in, const int* in_sizes, int n_in,
                              void* d_out, int out_size, void* d_ws, size_t ws_size,
                              hipStream_t stream) {
  const float* x     = (const float*)d_in[0];
  const float* Wq    = (const float*)d_in[1];
  const float* bq    = (const float*)d_in[2];
  const float* Wk    = (const float*)d_in[3];
  const float* bk    = (const float*)d_in[4];
  const float* Wv    = (const float*)d_in[5];
  const float* bv    = (const float*)d_in[6];
  const float* Wr    = (const float*)d_in[7];
  const float* br    = (const float*)d_in[8];
  const float* gamma = (const float*)d_in[9];
  const float* beta  = (const float*)d_in[10];
  const float* Wo    = (const float*)d_in[11];
  const float* bo    = (const float*)d_in[12];
  float* Z = (float*)d_out;

  char* ws = (char*)d_ws;
  float*  partial = (float*)(ws + OFF_PARTIAL);
  float*  lpart   = (float*)(ws + OFF_LPART);
  int*    idx     = (int*)(ws + OFF_IDX);
  float*  dist    = (float*)(ws + OFF_DIST);
  __bf16* WoT     = (__bf16*)(ws + OFF_WOT);
  __bf16* xb      = (__bf16*)(ws + OFF_XB);
  float*  Opart   = (float*)(ws + OFF_OPART);
  __bf16* Wt      = (__bf16*)(ws + OFF_WT);
  __bf16* Q       = (__bf16*)(ws + OFF_Q);
  __bf16* Ofin    = (__bf16*)(ws + OFF_OFIN);
  __bf16* K       = (__bf16*)(ws + OFF_K);
  __bf16* Vt      = (__bf16*)(ws + OFF_V);

  k_partial<<<dim3(32, B_), 256, 0, stream>>>(x, partial, xb);
  k_wt<<<dim3(16, 16, 3), 256, 0, stream>>>(Wq, Wk, Wv, Wt);
  k_wto<<<dim3(16, 4), 256, 0, stream>>>(Wo, WoT);
  k_stats<<<B_, 256, 0, stream>>>(partial, Wr, br, gamma, beta, idx, dist);
  k_qkv_mfma<<<dim3(S_ / 64, B_ * A_), 256, 0, stream>>>(xb, Wt, bq, bk, bv, idx, Q, K, Vt);
  k_attn_mfma<<<dim3(S_ / 64, B_ * A_, 2), 256, 0, stream>>>(Q, K, Vt, Opart, lpart);
  k_combine<<<2048, 256, 0, stream>>>(Opart, lpart, dist, Ofin);
  k_oproj_mfma<<<dim3(D_ / 128, (B_ * S_) / 128), 256, 0, stream>>>(Ofin, WoT, bo, Z);
}

// Round 15
// 176.483 us; speedup vs baseline: 1.2251x; 1.0874x over previous
//
#include <hip/hip_runtime.h>
#include <math.h>

#define B_ 8
#define S_ 2048
#define D_ 1024
#define H_ 16
#define A_ 4
#define DA_ 64
#define LN_EPS 1e-5f
// 0.125 * log2(e): Q pre-scale so softmax runs in exp2 domain
#define QSCALE 0.1803368801111204f
// fixed softmax reference (log2 units), folded into the QK accumulator init
#define MREF 20.0f

typedef __bf16 bf16x8 __attribute__((ext_vector_type(8)));
typedef __bf16 bf16x4 __attribute__((ext_vector_type(4)));
typedef float f32x4 __attribute__((ext_vector_type(4)));
typedef unsigned short u16x8 __attribute__((ext_vector_type(8)));

// ---------------- workspace layout (bytes) ----------------
// 0    : partial 1MB (k_partial->k_stats)
// 1MB  : idx ; 1MB+1K: dist ; 1.5MB: WoT bf16 512KB
// 2MB  : xb bf16 32MB (dead after qkv) -> Ofin bf16 8MB (attn->oproj)
// 34MB : Wt bf16 6MB ; 40MB: Q ; 48MB: K ; 56MB: Vt ([ba][da][s]). 64MB total.
static const size_t OFF_PARTIAL = 0;
static const size_t OFF_IDX     = (size_t)1 << 20;
static const size_t OFF_DIST    = ((size_t)1 << 20) + 1024;
static const size_t OFF_WOT     = ((size_t)1 << 20) + ((size_t)1 << 19);
static const size_t OFF_XB      = (size_t)2 << 20;
static const size_t OFF_OFIN    = OFF_XB;                    // xb dead after qkv
static const size_t OFF_WT      = (size_t)34 << 20;
static const size_t OFF_Q       = (size_t)40 << 20;
static const size_t OFF_K       = (size_t)48 << 20;
static const size_t OFF_V       = (size_t)56 << 20;

// ---------------- kernel 1: column-sum partial over S + bf16 convert ----------------
__global__ __launch_bounds__(256) void k_partial(const float* __restrict__ x,
                                                 float* __restrict__ partial,
                                                 __bf16* __restrict__ xb) {
  const int c = blockIdx.x, b = blockIdx.y, t = threadIdx.x;
  const size_t base = ((size_t)b * S_ + (size_t)c * 64) * D_;
  f32x4 acc = {0.f, 0.f, 0.f, 0.f};
  for (int s = 0; s < 64; ++s) {
    f32x4 v = *(const f32x4*)(x + base + (size_t)s * D_ + 4 * t);
    acc += v;
    bf16x4 o;
    #pragma unroll
    for (int j = 0; j < 4; ++j) o[j] = (__bf16)v[j];
    *(bf16x4*)(xb + base + (size_t)s * D_ + 4 * t) = o;
  }
  *(f32x4*)(partial + ((size_t)b * 32 + c) * D_ + 4 * t) = acc;
}

// ---------------- kernel 1b: transpose QKV weights to bf16 [m][n][k] ----------------
__global__ __launch_bounds__(256) void k_wt(const float* __restrict__ Wq,
                                            const float* __restrict__ Wk,
                                            const float* __restrict__ Wv,
                                            __bf16* __restrict__ Wt) {
  __shared__ float tsh[64][65];
  const int n0 = blockIdx.x * 64, k0 = blockIdx.y * 64, z = blockIdx.z;
  const float* W = (z == 0) ? Wq : (z == 1) ? Wk : Wv;
  const int t = threadIdx.x;
  #pragma unroll
  for (int i = 0; i < 4; ++i) {
    int r = i * 16 + (t >> 4), c = (t & 15) * 4;
    f32x4 v = *(const f32x4*)(W + (size_t)(k0 + r) * (H_ * DA_) + n0 + c);
    tsh[r][c + 0] = v[0]; tsh[r][c + 1] = v[1]; tsh[r][c + 2] = v[2]; tsh[r][c + 3] = v[3];
  }
  __syncthreads();
  #pragma unroll
  for (int i = 0; i < 4; ++i) {
    int n = i * 16 + (t >> 4), kc = (t & 15) * 4;
    bf16x4 o;
    #pragma unroll
    for (int j = 0; j < 4; ++j) o[j] = (__bf16)tsh[kc + j][n];
    *(bf16x4*)(Wt + (size_t)z * 1048576 + (size_t)(n0 + n) * 1024 + k0 + kc) = o;
  }
}

// ---------------- kernel 1c: transpose Wo [256][1024] -> WoT bf16 [1024][256] ----------------
__global__ __launch_bounds__(256) void k_wto(const float* __restrict__ Wo,
                                             __bf16* __restrict__ WoT) {
  __shared__ float tsh[64][65];
  const int n0 = blockIdx.x * 64, k0 = blockIdx.y * 64;
  const int t = threadIdx.x;
  #pragma unroll
  for (int i = 0; i < 4; ++i) {
    int r = i * 16 + (t >> 4), c = (t & 15) * 4;
    f32x4 v = *(const f32x4*)(Wo + (size_t)(k0 + r) * D_ + n0 + c);
    tsh[r][c + 0] = v[0]; tsh[r][c + 1] = v[1]; tsh[r][c + 2] = v[2]; tsh[r][c + 3] = v[3];
  }
  __syncthreads();
  #pragma unroll
  for (int i = 0; i < 4; ++i) {
    int n = i * 16 + (t >> 4), kc = (t & 15) * 4;
    bf16x4 o;
    #pragma unroll
    for (int j = 0; j < 4; ++j) o[j] = (__bf16)tsh[kc + j][n];
    *(bf16x4*)(WoT + (size_t)(n0 + n) * (A_ * DA_) + k0 + kc) = o;
  }
}

// ---------------- kernel 2: xbar -> r -> LN -> softmax -> top4 ----------------
__global__ __launch_bounds__(256) void k_stats(const float* __restrict__ partial,
                                               const float* __restrict__ Wr,
                                               const float* __restrict__ br,
                                               const float* __restrict__ gamma,
                                               const float* __restrict__ beta,
                                               int* __restrict__ idx_out,
                                               float* __restrict__ dist_out) {
  __shared__ float xbar[D_];
  __shared__ float rsh[H_];
  const int b = blockIdx.x, t = threadIdx.x;
  #pragma unroll
  for (int j = 0; j < 4; ++j) {
    int d = j * 256 + t;
    float s = 0.f;
    for (int c = 0; c < 32; ++c) s += partial[((size_t)b * 32 + c) * D_ + d];
    xbar[d] = s * (1.0f / S_);
  }
  __syncthreads();
  const int w = t >> 6, lane = t & 63;
  #pragma unroll
  for (int i = 0; i < 4; ++i) {
    int h = w * 4 + i;
    float s = 0.f;
    #pragma unroll
    for (int j = 0; j < 16; ++j) {
      int d = j * 64 + lane;
      s += xbar[d] * Wr[d * H_ + h];
    }
    for (int off = 32; off; off >>= 1) s += __shfl_down(s, off);
    if (lane == 0) rsh[h] = s + br[h];
  }
  __syncthreads();
  if (t == 0) {
    float r[H_];
    float mu = 0.f;
    for (int h = 0; h < H_; ++h) { r[h] = rsh[h]; mu += r[h]; }
    mu *= (1.0f / H_);
    float var = 0.f;
    for (int h = 0; h < H_; ++h) { float d = r[h] - mu; var += d * d; }
    var *= (1.0f / H_);
    float inv = rsqrtf(var + LN_EPS);
    float rn[H_], ex[H_];
    float mx = -1e30f;
    for (int h = 0; h < H_; ++h) {
      rn[h] = (r[h] - mu) * inv * gamma[h] + beta[h];
      mx = fmaxf(mx, rn[h]);
    }
    float sum = 0.f;
    for (int h = 0; h < H_; ++h) { ex[h] = expf(rn[h] - mx); sum += ex[h]; }
    int sel[A_];
    bool used[H_] = {false};
    for (int a = 0; a < A_; ++a) {
      int best = 0; float bv = -1.f;
      for (int h = 0; h < H_; ++h)
        if (!used[h] && ex[h] > bv) { bv = ex[h]; best = h; }
      used[best] = true; sel[a] = best;
    }
    for (int i = 0; i < A_; ++i)
      for (int j = i + 1; j < A_; ++j)
        if (sel[j] < sel[i]) { int tmp = sel[i]; sel[i] = sel[j]; sel[j] = tmp; }
    float invsum = 1.0f / sum;
    for (int a = 0; a < A_; ++a) {
      idx_out[b * A_ + a] = sel[a];
      dist_out[b * A_ + a] = ex[sel[a]] * invsum;
    }
  }
}

// ---------------- kernel 3: QKV projection, bf16 MFMA ----------------
// grid (S/64=32, B*A=32) = 1024 blocks (4/CU), block 256 (4 waves).
// Tile 64(M) x 192(N), BK=64. Wave owns 32x96 (2x6 frags). Async reg
// double-buffer staging. Q pre-scaled by QSCALE. V written TRANSPOSED
// (Vt[ba][da][s]) via an LDS bounce through the dead As buffer.
__global__ __launch_bounds__(256) void k_qkv_mfma(const __bf16* __restrict__ xb,
                                                  const __bf16* __restrict__ Wt,
                                                  const float* __restrict__ bq,
                                                  const float* __restrict__ bk,
                                                  const float* __restrict__ bv,
                                                  const int* __restrict__ idx,
                                                  __bf16* __restrict__ Q,
                                                  __bf16* __restrict__ K,
                                                  __bf16* __restrict__ Vt_g) {
  __shared__ unsigned short As[64][72];
  __shared__ unsigned short Bs[192][72];
  const int qt = blockIdx.x, ba = blockIdx.y;
  const int b = ba >> 2;
  const int head64 = idx[ba] * 64;
  const int t = threadIdx.x;
  const int w = t >> 6, l = t & 63, x = l & 15, g = l >> 4;
  const int MO = (w >> 1) * 32, NO = (w & 1) * 96;

  const unsigned short* xbu = (const unsigned short*)xb;
  const unsigned short* Wtu = (const unsigned short*)Wt;
  const size_t xbase = ((size_t)b * S_ + (size_t)qt * 64) * D_;

  u16x8 areg[2], breg[6];
  #pragma unroll
  for (int i = 0; i < 2; ++i) {
    int id = t + 256 * i, row = id >> 3, ch = id & 7;
    areg[i] = *(const u16x8*)(xbu + xbase + (size_t)row * D_ + ch * 8);
  }
  #pragma unroll
  for (int i = 0; i < 6; ++i) {
    int id = t + 256 * i, row = id >> 3, ch = id & 7;
    int m = row >> 6, nn = row & 63;
    breg[i] = *(const u16x8*)(Wtu + (size_t)m * 1048576 +
                              (size_t)(head64 + nn) * 1024 + ch * 8);
  }

  f32x4 acc[2][6];
  #pragma unroll
  for (int mf = 0; mf < 2; ++mf)
    #pragma unroll
    for (int nf = 0; nf < 6; ++nf) acc[mf][nf] = (f32x4){0.f, 0.f, 0.f, 0.f};

  for (int k0 = 0; k0 < D_; k0 += 64) {
    __syncthreads();
    #pragma unroll
    for (int i = 0; i < 2; ++i) {
      int id = t + 256 * i, row = id >> 3, ch = id & 7;
      *(u16x8*)&As[row][ch * 8] = areg[i];
    }
    #pragma unroll
    for (int i = 0; i < 6; ++i) {
      int id = t + 256 * i, row = id >> 3, ch = id & 7;
      *(u16x8*)&Bs[row][ch * 8] = breg[i];
    }
    __syncthreads();
    {
      int kn = (k0 + 64 < D_) ? k0 + 64 : k0;
      #pragma unroll
      for (int i = 0; i < 2; ++i) {
        int id = t + 256 * i, row = id >> 3, ch = id & 7;
        areg[i] = *(const u16x8*)(xbu + xbase + (size_t)row * D_ + kn + ch * 8);
      }
      #pragma unroll
      for (int i = 0; i < 6; ++i) {
        int id = t + 256 * i, row = id >> 3, ch = id & 7;
        int m = row >> 6, nn = row & 63;
        breg[i] = *(const u16x8*)(Wtu + (size_t)m * 1048576 +
                                  (size_t)(head64 + nn) * 1024 + kn + ch * 8);
      }
    }
    #pragma unroll
    for (int ks = 0; ks < 2; ++ks) {
      bf16x8 af[2], bfr[6];
      #pragma unroll
      for (int mf = 0; mf < 2; ++mf)
        af[mf] = *(const bf16x8*)&As[MO + mf * 16 + x][ks * 32 + g * 8];
      #pragma unroll
      for (int nf = 0; nf < 6; ++nf)
        bfr[nf] = *(const bf16x8*)&Bs[NO + nf * 16 + x][ks * 32 + g * 8];
      #pragma unroll
      for (int mf = 0; mf < 2; ++mf)
        #pragma unroll
        for (int nf = 0; nf < 6; ++nf)
          acc[mf][nf] = __builtin_amdgcn_mfma_f32_16x16x32_bf16(af[mf], bfr[nf], acc[mf][nf], 0, 0, 0);
    }
  }

  // ---- epilogue: Q and K direct (row-major); V via LDS bounce, transposed ----
  #pragma unroll
  for (int nf = 0; nf < 6; ++nf) {
    const int n = NO + nf * 16;
    const int m = n >> 6;
    if (m == 2) continue;                 // V handled by the bounce below
    const float* bias = (m == 0) ? bq : bk;
    __bf16* out = (m == 0) ? Q : K;
    const float sc = (m == 0) ? QSCALE : 1.0f;
    const int nn = (n & 63) + x;
    const float bval = bias[head64 + nn];
    #pragma unroll
    for (int mf = 0; mf < 2; ++mf)
      #pragma unroll
      for (int r = 0; r < 4; ++r) {
        int srow = qt * 64 + MO + mf * 16 + 4 * g + r;
        float val = (acc[mf][nf][r] + bval) * sc;
        out[((size_t)ba * S_ + srow) * DA_ + nn] = (__bf16)val;
      }
  }

  __syncthreads();                        // As dead (main loop done)
  if (w & 1) {                            // waves 1,3 own V (nf=2..5)
    #pragma unroll
    for (int nf = 2; nf < 6; ++nf) {
      const int da = (nf - 2) * 16 + x;
      const float bval = bv[head64 + da];
      #pragma unroll
      for (int mf = 0; mf < 2; ++mf)
        #pragma unroll
        for (int r = 0; r < 4; ++r) {
          int ls = MO + mf * 16 + 4 * g + r;   // local s-row 0..63
          __bf16 vb = (__bf16)(acc[mf][nf][r] + bval);
          As[da][ls] = __builtin_bit_cast(unsigned short, vb);
        }
    }
  }
  __syncthreads();
  {
    unsigned short* Vtu = (unsigned short*)Vt_g;
    const int vrow = t >> 3, vch = t & 7;
    u16x8 v0 = *(const u16x8*)&As[vrow][vch * 8];
    u16x8 v1 = *(const u16x8*)&As[vrow + 32][vch * 8];
    const size_t vb0 = (size_t)ba * DA_ * S_;
    *(u16x8*)(Vtu + vb0 + (size_t)vrow * S_ + qt * 64 + vch * 8) = v0;
    *(u16x8*)(Vtu + vb0 + (size_t)(vrow + 32) * S_ + qt * 64 + vch * 8) = v1;
  }
}

// ---------------- kernel 4: flash attention, bf16 MFMA 16x16x32 ----------------
// grid (S/64=32, B*A=32) = 1024 blocks (4/CU), block 256 (4 waves, 16 Q-rows
// each), 32 KV iters. r14-verified inner loop: V staged exactly like K
// (global Vt[ba][da][s] rows -> chunk-XOR b128 LDS writes); fixed-reference
// softmax with -MREF folded into the QK accumulator init; async reg
// double-buffer K/V staging. Direct bf16 Ofin write (no KV-split/combine).
__global__ __launch_bounds__(256, 4) void k_attn_mfma(const __bf16* __restrict__ Qg,
                                                      const __bf16* __restrict__ Kg,
                                                      const __bf16* __restrict__ Vtg,
                                                      const float* __restrict__ dist,
                                                      __bf16* __restrict__ Ofin) {
  __shared__ unsigned short QPs[64 * 72];  // Qs (stage, row*64) then Ps (row*72)
  __shared__ unsigned short Ks[64 * 64];   // chunk-XOR swizzled
  __shared__ unsigned short Vt[64 * 64];   // [da][kv], chunk-XOR swizzled

  const int qt = blockIdx.x, ba = blockIdx.y;
  const int b = ba >> 2, a = ba & 3;
  const int t = threadIdx.x;
  const int w = t >> 6, l = t & 63, x = l & 15, g = l >> 4;

  const unsigned short* Qgu = (const unsigned short*)Qg;
  const unsigned short* Kgu = (const unsigned short*)Kg;
  const unsigned short* Vgu = (const unsigned short*)Vtg;

  const size_t kvbase = (size_t)ba * S_ * DA_;   // K base ([s][da])
  const size_t vbase  = (size_t)ba * DA_ * S_;   // Vt base ([da][s])

  const int krow = t >> 3, kch = t & 7;

  // ---- prologue: issue K/V loads for tile 0 ----
  u16x8 kreg0, kreg1, vreg0, vreg1;
  kreg0 = *(const u16x8*)(Kgu + kvbase + (size_t)(krow) * 64 + kch * 8);
  kreg1 = *(const u16x8*)(Kgu + kvbase + (size_t)(krow + 32) * 64 + kch * 8);
  vreg0 = *(const u16x8*)(Vgu + vbase + (size_t)krow * S_ + kch * 8);
  vreg1 = *(const u16x8*)(Vgu + vbase + (size_t)(krow + 32) * S_ + kch * 8);

  // ---- stage Q tile (64 x 64) into QPs, chunk-XOR swizzle ----
  {
    const size_t qbase = ((size_t)ba * S_ + (size_t)qt * 64) * DA_;
    #pragma unroll
    for (int i = 0; i < 2; ++i) {
      int row = (t >> 3) + 32 * i;
      int ch = t & 7;
      u16x8 v = *(const u16x8*)(Qgu + qbase + (size_t)row * 64 + ch * 8);
      *(u16x8*)&QPs[row * 64 + ((ch ^ (row & 7)) << 3)] = v;
    }
  }
  __syncthreads();

  // ---- hoist Q fragments: wave w owns rows w*16..w*16+15 ----
  bf16x8 qf[2];
  #pragma unroll
  for (int ks = 0; ks < 2; ++ks) {
    int row = w * 16 + x;
    int ch = (g + 4 * ks) ^ (row & 7);
    qf[ks] = *(const bf16x8*)&QPs[row * 64 + (ch << 3)];
  }

  f32x4 o_[4];
  float l_[4];
  #pragma unroll
  for (int r = 0; r < 4; ++r) l_[r] = 0.f;
  #pragma unroll
  for (int nf = 0; nf < 4; ++nf) o_[nf] = (f32x4){0.f, 0.f, 0.f, 0.f};

  for (int kt = 0; kt < 32; ++kt) {
    __syncthreads();  // prior reads (incl. Q hoist on iter0) done
    *(u16x8*)&Ks[krow * 64 + ((kch ^ (krow & 7)) << 3)] = kreg0;
    *(u16x8*)&Vt[krow * 64 + ((kch ^ (krow & 7)) << 3)] = vreg0;
    {
      int row1 = krow + 32;
      *(u16x8*)&Ks[row1 * 64 + ((kch ^ (row1 & 7)) << 3)] = kreg1;
      *(u16x8*)&Vt[row1 * 64 + ((kch ^ (row1 & 7)) << 3)] = vreg1;
    }
    __syncthreads();

    // ---- issue async loads for tile kt+1 ----
    {
      int ktn = (kt + 1 < 32) ? kt + 1 : kt;
      kreg0 = *(const u16x8*)(Kgu + kvbase + (size_t)(ktn * 64 + krow) * 64 + kch * 8);
      kreg1 = *(const u16x8*)(Kgu + kvbase + (size_t)(ktn * 64 + krow + 32) * 64 + kch * 8);
      vreg0 = *(const u16x8*)(Vgu + vbase + (size_t)krow * S_ + ktn * 64 + kch * 8);
      vreg1 = *(const u16x8*)(Vgu + vbase + (size_t)(krow + 32) * S_ + ktn * 64 + kch * 8);
    }

    // ---- QK^T (exp2 domain), C-init = -MREF ----
    f32x4 s_[4];
    #pragma unroll
    for (int nf = 0; nf < 4; ++nf) s_[nf] = (f32x4){-MREF, -MREF, -MREF, -MREF};
    #pragma unroll
    for (int ks = 0; ks < 2; ++ks) {
      bf16x8 kf[4];
      #pragma unroll
      for (int nf = 0; nf < 4; ++nf) {
        int kvrow = nf * 16 + x;
        int ch = (g + 4 * ks) ^ (kvrow & 7);
        kf[nf] = *(const bf16x8*)&Ks[kvrow * 64 + (ch << 3)];
      }
      #pragma unroll
      for (int nf = 0; nf < 4; ++nf)
        s_[nf] = __builtin_amdgcn_mfma_f32_16x16x32_bf16(qf[ks], kf[nf], s_[nf], 0, 0, 0);
    }

    // ---- softmax numerator: p = exp2(s) (reference pre-subtracted) ----
    #pragma unroll
    for (int r = 0; r < 4; ++r) {
      float rs = 0.f;
      #pragma unroll
      for (int nf = 0; nf < 4; ++nf) {
        float p = exp2f(s_[nf][r]);
        s_[nf][r] = p;
        rs += p;
      }
      l_[r] += rs;
    }

    // ---- P -> LDS (wave-local rows in QPs) ----
    #pragma unroll
    for (int nf = 0; nf < 4; ++nf)
      #pragma unroll
      for (int r = 0; r < 4; ++r) {
        int row = w * 16 + 4 * g + r;
        int col = nf * 16 + x;
        __bf16 pb = (__bf16)s_[nf][r];
        QPs[row * 72 + col] = __builtin_bit_cast(unsigned short, pb);
      }

    // ---- PV: O += P @ V ----
    #pragma unroll
    for (int ks = 0; ks < 2; ++ks) {
      bf16x8 pf = *(const bf16x8*)&QPs[(w * 16 + x) * 72 + (g * 8 + ks * 32)];
      bf16x8 vf[4];
      #pragma unroll
      for (int nf = 0; nf < 4; ++nf) {
        int darow = nf * 16 + x;
        int ch = (g + 4 * ks) ^ (darow & 7);
        vf[nf] = *(const bf16x8*)&Vt[darow * 64 + (ch << 3)];
      }
      #pragma unroll
      for (int nf = 0; nf < 4; ++nf)
        o_[nf] = __builtin_amdgcn_mfma_f32_16x16x32_bf16(pf, vf[nf], o_[nf], 0, 0, 0);
    }
  }

  // ---- epilogue: reduce per-lane l across the 16 x-lanes, scale, write bf16 ----
  const float dd = dist[ba];
  {
    float inv[4];
    #pragma unroll
    for (int r = 0; r < 4; ++r) {
      float lr = l_[r];
      lr += __shfl_xor(lr, 1);
      lr += __shfl_xor(lr, 2);
      lr += __shfl_xor(lr, 4);
      lr += __shfl_xor(lr, 8);
      inv[r] = dd / lr;
    }
    #pragma unroll
    for (int nf = 0; nf < 4; ++nf)
      #pragma unroll
      for (int r = 0; r < 4; ++r) {
        int row = qt * 64 + w * 16 + 4 * g + r;
        int col = nf * 16 + x;
        Ofin[((size_t)b * S_ + row) * (A_ * DA_) + a * DA_ + col] =
            (__bf16)(o_[nf][r] * inv[r]);
      }
  }
}

// ---------------- kernel 5: output projection, bf16 MFMA (async reg dbuf) ----------------
__global__ __launch_bounds__(256) void k_oproj_mfma(const __bf16* __restrict__ Of,
                                                    const __bf16* __restrict__ WoT,
                                                    const float* __restrict__ bo,
                                                    float* __restrict__ Z) {
  __shared__ unsigned short As[128][72];
  __shared__ unsigned short Bs[128][72];
  const int nt = blockIdx.x, mt = blockIdx.y;
  const int t = threadIdx.x;
  const int w = t >> 6, l = t & 63, x = l & 15, g = l >> 4;
  const int MO = (w >> 1) * 64, NO = (w & 1) * 64;

  const unsigned short* Ofu = (const unsigned short*)Of;
  const unsigned short* Wu  = (const unsigned short*)WoT;

  // prologue: load k-step 0 into regs
  u16x8 areg[4], breg[4];
  #pragma unroll
  for (int i = 0; i < 4; ++i) {
    int id = t + 256 * i, row = id >> 3, ch = id & 7;
    areg[i] = *(const u16x8*)(Ofu + ((size_t)(mt * 128 + row)) * (A_ * DA_) + ch * 8);
    breg[i] = *(const u16x8*)(Wu + ((size_t)(nt * 128 + row)) * (A_ * DA_) + ch * 8);
  }

  f32x4 acc[4][4];
  #pragma unroll
  for (int mf = 0; mf < 4; ++mf)
    #pragma unroll
    for (int nf = 0; nf < 4; ++nf) acc[mf][nf] = (f32x4){0.f, 0.f, 0.f, 0.f};

  for (int k0 = 0; k0 < A_ * DA_; k0 += 64) {
    __syncthreads();
    #pragma unroll
    for (int i = 0; i < 4; ++i) {
      int id = t + 256 * i, row = id >> 3, ch = id & 7;
      *(u16x8*)&As[row][ch * 8] = areg[i];
      *(u16x8*)&Bs[row][ch * 8] = breg[i];
    }
    __syncthreads();
    {
      int kn = (k0 + 64 < A_ * DA_) ? k0 + 64 : k0;
      #pragma unroll
      for (int i = 0; i < 4; ++i) {
        int id = t + 256 * i, row = id >> 3, ch = id & 7;
        areg[i] = *(const u16x8*)(Ofu + ((size_t)(mt * 128 + row)) * (A_ * DA_) + kn + ch * 8);
        breg[i] = *(const u16x8*)(Wu + ((size_t)(nt * 128 + row)) * (A_ * DA_) + kn + ch * 8);
      }
    }
    #pragma unroll
    for (int ks = 0; ks < 2; ++ks) {
      bf16x8 af[4], bfr[4];
      #pragma unroll
      for (int mf = 0; mf < 4; ++mf)
        af[mf] = *(const bf16x8*)&As[MO + mf * 16 + x][ks * 32 + g * 8];
      #pragma unroll
      for (int nf = 0; nf < 4; ++nf)
        bfr[nf] = *(const bf16x8*)&Bs[NO + nf * 16 + x][ks * 32 + g * 8];
      #pragma unroll
      for (int mf = 0; mf < 4; ++mf)
        #pragma unroll
        for (int nf = 0; nf < 4; ++nf)
          acc[mf][nf] = __builtin_amdgcn_mfma_f32_16x16x32_bf16(af[mf], bfr[nf], acc[mf][nf], 0, 0, 0);
    }
  }

  #pragma unroll
  for (int nf = 0; nf < 4; ++nf) {
    const int n = nt * 128 + NO + nf * 16 + x;
    const float bval = bo[n];
    #pragma unroll
    for (int mf = 0; mf < 4; ++mf)
      #pragma unroll
      for (int r = 0; r < 4; ++r) {
        int row = mt * 128 + MO + mf * 16 + 4 * g + r;
        Z[(size_t)row * D_ + n] = acc[mf][nf][r] + bval;
      }
  }
}

extern "C" void kernel_launch(void* const* d_in, const int* in_sizes, int n_in,
                              void* d_out, int out_size, void* d_ws, size_t ws_size,
                              hipStream_t stream) {
  const float* x     = (const float*)d_in[0];
  const float* Wq    = (const float*)d_in[1];
  const float* bq    = (const float*)d_in[2];
  const float* Wk    = (const float*)d_in[3];
  const float* bk    = (const float*)d_in[4];
  const float* Wv    = (const float*)d_in[5];
  const float* bv    = (const float*)d_in[6];
  const float* Wr    = (const float*)d_in[7];
  const float* br    = (const float*)d_in[8];
  const float* gamma = (const float*)d_in[9];
  const float* beta  = (const float*)d_in[10];
  const float* Wo    = (const float*)d_in[11];
  const float* bo    = (const float*)d_in[12];
  float* Z = (float*)d_out;

  char* ws = (char*)d_ws;
  float*  partial = (float*)(ws + OFF_PARTIAL);
  int*    idx     = (int*)(ws + OFF_IDX);
  float*  dist    = (float*)(ws + OFF_DIST);
  __bf16* WoT     = (__bf16*)(ws + OFF_WOT);
  __bf16* xb      = (__bf16*)(ws + OFF_XB);
  __bf16* Wt      = (__bf16*)(ws + OFF_WT);
  __bf16* Q       = (__bf16*)(ws + OFF_Q);
  __bf16* Ofin    = (__bf16*)(ws + OFF_OFIN);
  __bf16* K       = (__bf16*)(ws + OFF_K);
  __bf16* Vt      = (__bf16*)(ws + OFF_V);

  k_partial<<<dim3(32, B_), 256, 0, stream>>>(x, partial, xb);
  k_wt<<<dim3(16, 16, 3), 256, 0, stream>>>(Wq, Wk, Wv, Wt);
  k_wto<<<dim3(16, 4), 256, 0, stream>>>(Wo, WoT);
  k_stats<<<B_, 256, 0, stream>>>(partial, Wr, br, gamma, beta, idx, dist);
  k_qkv_mfma<<<dim3(S_ / 64, B_ * A_), 256, 0, stream>>>(xb, Wt, bq, bk, bv, idx, Q, K, Vt);
  k_attn_mfma<<<dim3(S_ / 64, B_ * A_), 256, 0, stream>>>(Q, K, Vt, dist, Ofin);
  k_oproj_mfma<<<dim3(D_ / 128, (B_ * S_) / 128), 256, 0, stream>>>(Ofin, WoT, bo, Z);
}

// Round 16
// 169.883 us; speedup vs baseline: 1.2727x; 1.0388x over previous
//
#include <hip/hip_runtime.h>
#include <math.h>

#define B_ 8
#define S_ 2048
#define D_ 1024
#define H_ 16
#define A_ 4
#define DA_ 64
#define LN_EPS 1e-5f
// 0.125 * log2(e): Q pre-scale so softmax runs in exp2 domain
#define QSCALE 0.1803368801111204f
// fixed softmax reference (log2 units), folded into the QK accumulator init
#define MREF 20.0f

typedef __bf16 bf16x8 __attribute__((ext_vector_type(8)));
typedef __bf16 bf16x4 __attribute__((ext_vector_type(4)));
typedef float f32x4 __attribute__((ext_vector_type(4)));
typedef unsigned short u16x8 __attribute__((ext_vector_type(8)));
typedef unsigned short u16x4 __attribute__((ext_vector_type(4)));

// ---------------- workspace layout (bytes) ----------------
static const size_t OFF_PARTIAL = 0;
static const size_t OFF_IDX     = (size_t)1 << 20;
static const size_t OFF_DIST    = ((size_t)1 << 20) + 1024;
static const size_t OFF_WOT     = ((size_t)1 << 20) + ((size_t)1 << 19);
static const size_t OFF_XB      = (size_t)2 << 20;
static const size_t OFF_OFIN    = OFF_XB;                    // xb dead after qkv
static const size_t OFF_WT      = (size_t)34 << 20;
static const size_t OFF_Q       = (size_t)40 << 20;
static const size_t OFF_K       = (size_t)48 << 20;
static const size_t OFF_V       = (size_t)56 << 20;

// ---------------- kernel 1: column-sum partial over S + bf16 convert ----------------
__global__ __launch_bounds__(256) void k_partial(const float* __restrict__ x,
                                                 float* __restrict__ partial,
                                                 __bf16* __restrict__ xb) {
  const int c = blockIdx.x, b = blockIdx.y, t = threadIdx.x;
  const size_t base = ((size_t)b * S_ + (size_t)c * 64) * D_;
  f32x4 acc = {0.f, 0.f, 0.f, 0.f};
  for (int s = 0; s < 64; ++s) {
    f32x4 v = *(const f32x4*)(x + base + (size_t)s * D_ + 4 * t);
    acc += v;
    bf16x4 o;
    #pragma unroll
    for (int j = 0; j < 4; ++j) o[j] = (__bf16)v[j];
    *(bf16x4*)(xb + base + (size_t)s * D_ + 4 * t) = o;
  }
  *(f32x4*)(partial + ((size_t)b * 32 + c) * D_ + 4 * t) = acc;
}

// ---------------- kernel 1b: transpose QKV weights to bf16 [m][n][k] ----------------
__global__ __launch_bounds__(256) void k_wt(const float* __restrict__ Wq,
                                            const float* __restrict__ Wk,
                                            const float* __restrict__ Wv,
                                            __bf16* __restrict__ Wt) {
  __shared__ float tsh[64][65];
  const int n0 = blockIdx.x * 64, k0 = blockIdx.y * 64, z = blockIdx.z;
  const float* W = (z == 0) ? Wq : (z == 1) ? Wk : Wv;
  const int t = threadIdx.x;
  #pragma unroll
  for (int i = 0; i < 4; ++i) {
    int r = i * 16 + (t >> 4), c = (t & 15) * 4;
    f32x4 v = *(const f32x4*)(W + (size_t)(k0 + r) * (H_ * DA_) + n0 + c);
    tsh[r][c + 0] = v[0]; tsh[r][c + 1] = v[1]; tsh[r][c + 2] = v[2]; tsh[r][c + 3] = v[3];
  }
  __syncthreads();
  #pragma unroll
  for (int i = 0; i < 4; ++i) {
    int n = i * 16 + (t >> 4), kc = (t & 15) * 4;
    bf16x4 o;
    #pragma unroll
    for (int j = 0; j < 4; ++j) o[j] = (__bf16)tsh[kc + j][n];
    *(bf16x4*)(Wt + (size_t)z * 1048576 + (size_t)(n0 + n) * 1024 + k0 + kc) = o;
  }
}

// ---------------- kernel 1c: transpose Wo [256][1024] -> WoT bf16 [1024][256] ----------------
__global__ __launch_bounds__(256) void k_wto(const float* __restrict__ Wo,
                                             __bf16* __restrict__ WoT) {
  __shared__ float tsh[64][65];
  const int n0 = blockIdx.x * 64, k0 = blockIdx.y * 64;
  const int t = threadIdx.x;
  #pragma unroll
  for (int i = 0; i < 4; ++i) {
    int r = i * 16 + (t >> 4), c = (t & 15) * 4;
    f32x4 v = *(const f32x4*)(Wo + (size_t)(k0 + r) * D_ + n0 + c);
    tsh[r][c + 0] = v[0]; tsh[r][c + 1] = v[1]; tsh[r][c + 2] = v[2]; tsh[r][c + 3] = v[3];
  }
  __syncthreads();
  #pragma unroll
  for (int i = 0; i < 4; ++i) {
    int n = i * 16 + (t >> 4), kc = (t & 15) * 4;
    bf16x4 o;
    #pragma unroll
    for (int j = 0; j < 4; ++j) o[j] = (__bf16)tsh[kc + j][n];
    *(bf16x4*)(WoT + (size_t)(n0 + n) * (A_ * DA_) + k0 + kc) = o;
  }
}

// ---------------- kernel 2: xbar -> r -> LN -> softmax -> top4 ----------------
__global__ __launch_bounds__(256) void k_stats(const float* __restrict__ partial,
                                               const float* __restrict__ Wr,
                                               const float* __restrict__ br,
                                               const float* __restrict__ gamma,
                                               const float* __restrict__ beta,
                                               int* __restrict__ idx_out,
                                               float* __restrict__ dist_out) {
  __shared__ float xbar[D_];
  __shared__ float rsh[H_];
  const int b = blockIdx.x, t = threadIdx.x;
  #pragma unroll
  for (int j = 0; j < 4; ++j) {
    int d = j * 256 + t;
    float s = 0.f;
    for (int c = 0; c < 32; ++c) s += partial[((size_t)b * 32 + c) * D_ + d];
    xbar[d] = s * (1.0f / S_);
  }
  __syncthreads();
  const int w = t >> 6, lane = t & 63;
  #pragma unroll
  for (int i = 0; i < 4; ++i) {
    int h = w * 4 + i;
    float s = 0.f;
    #pragma unroll
    for (int j = 0; j < 16; ++j) {
      int d = j * 64 + lane;
      s += xbar[d] * Wr[d * H_ + h];
    }
    for (int off = 32; off; off >>= 1) s += __shfl_down(s, off);
    if (lane == 0) rsh[h] = s + br[h];
  }
  __syncthreads();
  if (t == 0) {
    float r[H_];
    float mu = 0.f;
    for (int h = 0; h < H_; ++h) { r[h] = rsh[h]; mu += r[h]; }
    mu *= (1.0f / H_);
    float var = 0.f;
    for (int h = 0; h < H_; ++h) { float d = r[h] - mu; var += d * d; }
    var *= (1.0f / H_);
    float inv = rsqrtf(var + LN_EPS);
    float rn[H_], ex[H_];
    float mx = -1e30f;
    for (int h = 0; h < H_; ++h) {
      rn[h] = (r[h] - mu) * inv * gamma[h] + beta[h];
      mx = fmaxf(mx, rn[h]);
    }
    float sum = 0.f;
    for (int h = 0; h < H_; ++h) { ex[h] = expf(rn[h] - mx); sum += ex[h]; }
    int sel[A_];
    bool used[H_] = {false};
    for (int a = 0; a < A_; ++a) {
      int best = 0; float bv = -1.f;
      for (int h = 0; h < H_; ++h)
        if (!used[h] && ex[h] > bv) { bv = ex[h]; best = h; }
      used[best] = true; sel[a] = best;
    }
    for (int i = 0; i < A_; ++i)
      for (int j = i + 1; j < A_; ++j)
        if (sel[j] < sel[i]) { int tmp = sel[i]; sel[i] = sel[j]; sel[j] = tmp; }
    float invsum = 1.0f / sum;
    for (int a = 0; a < A_; ++a) {
      idx_out[b * A_ + a] = sel[a];
      dist_out[b * A_ + a] = ex[sel[a]] * invsum;
    }
  }
}

// ---------------- kernel 3: QKV projection, bf16 MFMA ----------------
// grid (S/64=32, B*A=32) = 1024 blocks (4/CU), block 256 (4 waves).
// Tile 64(M) x 192(N), BK=64. Wave owns 32x96 (2x6 frags). Async reg
// double-buffer staging. Q pre-scaled by QSCALE. V written TRANSPOSED
// (Vt[ba][da][s]) via an LDS bounce through the dead As buffer.
__global__ __launch_bounds__(256) void k_qkv_mfma(const __bf16* __restrict__ xb,
                                                  const __bf16* __restrict__ Wt,
                                                  const float* __restrict__ bq,
                                                  const float* __restrict__ bk,
                                                  const float* __restrict__ bv,
                                                  const int* __restrict__ idx,
                                                  __bf16* __restrict__ Q,
                                                  __bf16* __restrict__ K,
                                                  __bf16* __restrict__ Vt_g) {
  __shared__ unsigned short As[64][72];
  __shared__ unsigned short Bs[192][72];
  const int qt = blockIdx.x, ba = blockIdx.y;
  const int b = ba >> 2;
  const int head64 = idx[ba] * 64;
  const int t = threadIdx.x;
  const int w = t >> 6, l = t & 63, x = l & 15, g = l >> 4;
  const int MO = (w >> 1) * 32, NO = (w & 1) * 96;

  const unsigned short* xbu = (const unsigned short*)xb;
  const unsigned short* Wtu = (const unsigned short*)Wt;
  const size_t xbase = ((size_t)b * S_ + (size_t)qt * 64) * D_;

  u16x8 areg[2], breg[6];
  #pragma unroll
  for (int i = 0; i < 2; ++i) {
    int id = t + 256 * i, row = id >> 3, ch = id & 7;
    areg[i] = *(const u16x8*)(xbu + xbase + (size_t)row * D_ + ch * 8);
  }
  #pragma unroll
  for (int i = 0; i < 6; ++i) {
    int id = t + 256 * i, row = id >> 3, ch = id & 7;
    int m = row >> 6, nn = row & 63;
    breg[i] = *(const u16x8*)(Wtu + (size_t)m * 1048576 +
                              (size_t)(head64 + nn) * 1024 + ch * 8);
  }

  f32x4 acc[2][6];
  #pragma unroll
  for (int mf = 0; mf < 2; ++mf)
    #pragma unroll
    for (int nf = 0; nf < 6; ++nf) acc[mf][nf] = (f32x4){0.f, 0.f, 0.f, 0.f};

  for (int k0 = 0; k0 < D_; k0 += 64) {
    __syncthreads();
    #pragma unroll
    for (int i = 0; i < 2; ++i) {
      int id = t + 256 * i, row = id >> 3, ch = id & 7;
      *(u16x8*)&As[row][ch * 8] = areg[i];
    }
    #pragma unroll
    for (int i = 0; i < 6; ++i) {
      int id = t + 256 * i, row = id >> 3, ch = id & 7;
      *(u16x8*)&Bs[row][ch * 8] = breg[i];
    }
    __syncthreads();
    {
      int kn = (k0 + 64 < D_) ? k0 + 64 : k0;
      #pragma unroll
      for (int i = 0; i < 2; ++i) {
        int id = t + 256 * i, row = id >> 3, ch = id & 7;
        areg[i] = *(const u16x8*)(xbu + xbase + (size_t)row * D_ + kn + ch * 8);
      }
      #pragma unroll
      for (int i = 0; i < 6; ++i) {
        int id = t + 256 * i, row = id >> 3, ch = id & 7;
        int m = row >> 6, nn = row & 63;
        breg[i] = *(const u16x8*)(Wtu + (size_t)m * 1048576 +
                                  (size_t)(head64 + nn) * 1024 + kn + ch * 8);
      }
    }
    #pragma unroll
    for (int ks = 0; ks < 2; ++ks) {
      bf16x8 af[2], bfr[6];
      #pragma unroll
      for (int mf = 0; mf < 2; ++mf)
        af[mf] = *(const bf16x8*)&As[MO + mf * 16 + x][ks * 32 + g * 8];
      #pragma unroll
      for (int nf = 0; nf < 6; ++nf)
        bfr[nf] = *(const bf16x8*)&Bs[NO + nf * 16 + x][ks * 32 + g * 8];
      #pragma unroll
      for (int mf = 0; mf < 2; ++mf)
        #pragma unroll
        for (int nf = 0; nf < 6; ++nf)
          acc[mf][nf] = __builtin_amdgcn_mfma_f32_16x16x32_bf16(af[mf], bfr[nf], acc[mf][nf], 0, 0, 0);
    }
  }

  // ---- epilogue: Q and K direct (row-major); V via LDS bounce, transposed ----
  #pragma unroll
  for (int nf = 0; nf < 6; ++nf) {
    const int n = NO + nf * 16;
    const int m = n >> 6;
    if (m == 2) continue;                 // V handled by the bounce below
    const float* bias = (m == 0) ? bq : bk;
    __bf16* out = (m == 0) ? Q : K;
    const float sc = (m == 0) ? QSCALE : 1.0f;
    const int nn = (n & 63) + x;
    const float bval = bias[head64 + nn];
    #pragma unroll
    for (int mf = 0; mf < 2; ++mf)
      #pragma unroll
      for (int r = 0; r < 4; ++r) {
        int srow = qt * 64 + MO + mf * 16 + 4 * g + r;
        float val = (acc[mf][nf][r] + bval) * sc;
        out[((size_t)ba * S_ + srow) * DA_ + nn] = (__bf16)val;
      }
  }

  __syncthreads();                        // As dead (main loop done)
  if (w & 1) {                            // waves 1,3 own V (nf=2..5)
    #pragma unroll
    for (int nf = 2; nf < 6; ++nf) {
      const int da = (nf - 2) * 16 + x;
      const float bval = bv[head64 + da];
      #pragma unroll
      for (int mf = 0; mf < 2; ++mf)
        #pragma unroll
        for (int r = 0; r < 4; ++r) {
          int ls = MO + mf * 16 + 4 * g + r;   // local s-row 0..63
          __bf16 vb = (__bf16)(acc[mf][nf][r] + bval);
          As[da][ls] = __builtin_bit_cast(unsigned short, vb);
        }
    }
  }
  __syncthreads();
  {
    unsigned short* Vtu = (unsigned short*)Vt_g;
    const int vrow = t >> 3, vch = t & 7;
    u16x8 v0 = *(const u16x8*)&As[vrow][vch * 8];
    u16x8 v1 = *(const u16x8*)&As[vrow + 32][vch * 8];
    const size_t vb0 = (size_t)ba * DA_ * S_;
    *(u16x8*)(Vtu + vb0 + (size_t)vrow * S_ + qt * 64 + vch * 8) = v0;
    *(u16x8*)(Vtu + vb0 + (size_t)(vrow + 32) * S_ + qt * 64 + vch * 8) = v1;
  }
}

// ---------------- kernel 4: flash attention, bf16 MFMA 16x16x32 ----------------
// grid (S/64=32, B*A=32) = 1024 blocks (4/CU), block 256 (4 waves, 16 Q-rows
// each), 32 KV iters. SWAPPED QK^T: s = mfma(K, Q) so each lane holds 4
// CONSECUTIVE kv of one q-row (q = lane&15) -> P stored with 4 packed
// ds_write_b64 instead of 16 ds_write_b16; softmax l is a single scalar
// per lane (reduced across g-lanes in the epilogue). V staged like K from
// global Vt[ba][da][s]; fixed-reference softmax (-MREF in C-init); async
// reg double-buffer staging. All r14/r15-verified pieces retained.
__global__ __launch_bounds__(256, 4) void k_attn_mfma(const __bf16* __restrict__ Qg,
                                                      const __bf16* __restrict__ Kg,
                                                      const __bf16* __restrict__ Vtg,
                                                      const float* __restrict__ dist,
                                                      __bf16* __restrict__ Ofin) {
  __shared__ unsigned short QPs[64 * 72];  // Qs (stage, row*64) then Ps (row*72)
  __shared__ unsigned short Ks[64 * 64];   // chunk-XOR swizzled
  __shared__ unsigned short Vt[64 * 64];   // [da][kv], chunk-XOR swizzled

  const int qt = blockIdx.x, ba = blockIdx.y;
  const int b = ba >> 2, a = ba & 3;
  const int t = threadIdx.x;
  const int w = t >> 6, l = t & 63, x = l & 15, g = l >> 4;

  const unsigned short* Qgu = (const unsigned short*)Qg;
  const unsigned short* Kgu = (const unsigned short*)Kg;
  const unsigned short* Vgu = (const unsigned short*)Vtg;

  const size_t kvbase = (size_t)ba * S_ * DA_;   // K base ([s][da])
  const size_t vbase  = (size_t)ba * DA_ * S_;   // Vt base ([da][s])

  const int krow = t >> 3, kch = t & 7;

  // ---- prologue: issue K/V loads for tile 0 ----
  u16x8 kreg0, kreg1, vreg0, vreg1;
  kreg0 = *(const u16x8*)(Kgu + kvbase + (size_t)(krow) * 64 + kch * 8);
  kreg1 = *(const u16x8*)(Kgu + kvbase + (size_t)(krow + 32) * 64 + kch * 8);
  vreg0 = *(const u16x8*)(Vgu + vbase + (size_t)krow * S_ + kch * 8);
  vreg1 = *(const u16x8*)(Vgu + vbase + (size_t)(krow + 32) * S_ + kch * 8);

  // ---- stage Q tile (64 x 64) into QPs, chunk-XOR swizzle ----
  {
    const size_t qbase = ((size_t)ba * S_ + (size_t)qt * 64) * DA_;
    #pragma unroll
    for (int i = 0; i < 2; ++i) {
      int row = (t >> 3) + 32 * i;
      int ch = t & 7;
      u16x8 v = *(const u16x8*)(Qgu + qbase + (size_t)row * 64 + ch * 8);
      *(u16x8*)&QPs[row * 64 + ((ch ^ (row & 7)) << 3)] = v;
    }
  }
  __syncthreads();

  // ---- hoist Q fragments: wave w owns rows w*16..w*16+15 ----
  bf16x8 qf[2];
  #pragma unroll
  for (int ks = 0; ks < 2; ++ks) {
    int row = w * 16 + x;
    int ch = (g + 4 * ks) ^ (row & 7);
    qf[ks] = *(const bf16x8*)&QPs[row * 64 + (ch << 3)];
  }

  f32x4 o_[4];
  float l_lane = 0.f;
  #pragma unroll
  for (int nf = 0; nf < 4; ++nf) o_[nf] = (f32x4){0.f, 0.f, 0.f, 0.f};

  for (int kt = 0; kt < 32; ++kt) {
    __syncthreads();  // prior reads (incl. Q hoist on iter0) done
    *(u16x8*)&Ks[krow * 64 + ((kch ^ (krow & 7)) << 3)] = kreg0;
    *(u16x8*)&Vt[krow * 64 + ((kch ^ (krow & 7)) << 3)] = vreg0;
    {
      int row1 = krow + 32;
      *(u16x8*)&Ks[row1 * 64 + ((kch ^ (row1 & 7)) << 3)] = kreg1;
      *(u16x8*)&Vt[row1 * 64 + ((kch ^ (row1 & 7)) << 3)] = vreg1;
    }
    __syncthreads();

    // ---- issue async loads for tile kt+1 ----
    {
      int ktn = (kt + 1 < 32) ? kt + 1 : kt;
      kreg0 = *(const u16x8*)(Kgu + kvbase + (size_t)(ktn * 64 + krow) * 64 + kch * 8);
      kreg1 = *(const u16x8*)(Kgu + kvbase + (size_t)(ktn * 64 + krow + 32) * 64 + kch * 8);
      vreg0 = *(const u16x8*)(Vgu + vbase + (size_t)krow * S_ + ktn * 64 + kch * 8);
      vreg1 = *(const u16x8*)(Vgu + vbase + (size_t)(krow + 32) * S_ + ktn * 64 + kch * 8);
    }

    // ---- SWAPPED QK^T (exp2 domain), C-init = -MREF ----
    // s_[nf][r] = S[q = w*16 + x][kv = nf*16 + 4g + r] - MREF
    f32x4 s_[4];
    #pragma unroll
    for (int nf = 0; nf < 4; ++nf) s_[nf] = (f32x4){-MREF, -MREF, -MREF, -MREF};
    #pragma unroll
    for (int ks = 0; ks < 2; ++ks) {
      bf16x8 kf[4];
      #pragma unroll
      for (int nf = 0; nf < 4; ++nf) {
        int kvrow = nf * 16 + x;
        int ch = (g + 4 * ks) ^ (kvrow & 7);
        kf[nf] = *(const bf16x8*)&Ks[kvrow * 64 + (ch << 3)];
      }
      #pragma unroll
      for (int nf = 0; nf < 4; ++nf)
        s_[nf] = __builtin_amdgcn_mfma_f32_16x16x32_bf16(kf[nf], qf[ks], s_[nf], 0, 0, 0);
    }

    // ---- softmax numerator: p = exp2(s); single per-lane l partial ----
    float rs = 0.f;
    #pragma unroll
    for (int nf = 0; nf < 4; ++nf)
      #pragma unroll
      for (int r = 0; r < 4; ++r) {
        float p = exp2f(s_[nf][r]);
        s_[nf][r] = p;
        rs += p;
      }
    l_lane += rs;

    // ---- P -> LDS: 4 packed b64 writes at [q=x][kv=nf*16+4g] ----
    #pragma unroll
    for (int nf = 0; nf < 4; ++nf) {
      u16x4 pk;
      #pragma unroll
      for (int r = 0; r < 4; ++r) {
        __bf16 pb = (__bf16)s_[nf][r];
        pk[r] = __builtin_bit_cast(unsigned short, pb);
      }
      *(u16x4*)&QPs[(w * 16 + x) * 72 + nf * 16 + 4 * g] = pk;
    }

    // ---- PV: O += P @ V (unchanged orientation) ----
    #pragma unroll
    for (int ks = 0; ks < 2; ++ks) {
      bf16x8 pf = *(const bf16x8*)&QPs[(w * 16 + x) * 72 + (g * 8 + ks * 32)];
      bf16x8 vf[4];
      #pragma unroll
      for (int nf = 0; nf < 4; ++nf) {
        int darow = nf * 16 + x;
        int ch = (g + 4 * ks) ^ (darow & 7);
        vf[nf] = *(const bf16x8*)&Vt[darow * 64 + (ch << 3)];
      }
      #pragma unroll
      for (int nf = 0; nf < 4; ++nf)
        o_[nf] = __builtin_amdgcn_mfma_f32_16x16x32_bf16(pf, vf[nf], o_[nf], 0, 0, 0);
    }
  }

  // ---- epilogue: reduce l across g-lanes, route to output rows, write bf16 ----
  const float dd = dist[ba];
  {
    float lf = l_lane;
    lf += __shfl_xor(lf, 16);
    lf += __shfl_xor(lf, 32);            // all g-lanes now hold full l[q = x]
    float inv[4];
    #pragma unroll
    for (int r = 0; r < 4; ++r) {
      float lr = __shfl(lf, 4 * g + r);  // l for output row w*16 + 4g + r
      inv[r] = dd / lr;
    }
    #pragma unroll
    for (int nf = 0; nf < 4; ++nf)
      #pragma unroll
      for (int r = 0; r < 4; ++r) {
        int row = qt * 64 + w * 16 + 4 * g + r;
        int col = nf * 16 + x;
        Ofin[((size_t)b * S_ + row) * (A_ * DA_) + a * DA_ + col] =
            (__bf16)(o_[nf][r] * inv[r]);
      }
  }
}

// ---------------- kernel 5: output projection, bf16 MFMA (async reg dbuf) ----------------
__global__ __launch_bounds__(256) void k_oproj_mfma(const __bf16* __restrict__ Of,
                                                    const __bf16* __restrict__ WoT,
                                                    const float* __restrict__ bo,
                                                    float* __restrict__ Z) {
  __shared__ unsigned short As[128][72];
  __shared__ unsigned short Bs[128][72];
  const int nt = blockIdx.x, mt = blockIdx.y;
  const int t = threadIdx.x;
  const int w = t >> 6, l = t & 63, x = l & 15, g = l >> 4;
  const int MO = (w >> 1) * 64, NO = (w & 1) * 64;

  const unsigned short* Ofu = (const unsigned short*)Of;
  const unsigned short* Wu  = (const unsigned short*)WoT;

  u16x8 areg[4], breg[4];
  #pragma unroll
  for (int i = 0; i < 4; ++i) {
    int id = t + 256 * i, row = id >> 3, ch = id & 7;
    areg[i] = *(const u16x8*)(Ofu + ((size_t)(mt * 128 + row)) * (A_ * DA_) + ch * 8);
    breg[i] = *(const u16x8*)(Wu + ((size_t)(nt * 128 + row)) * (A_ * DA_) + ch * 8);
  }

  f32x4 acc[4][4];
  #pragma unroll
  for (int mf = 0; mf < 4; ++mf)
    #pragma unroll
    for (int nf = 0; nf < 4; ++nf) acc[mf][nf] = (f32x4){0.f, 0.f, 0.f, 0.f};

  for (int k0 = 0; k0 < A_ * DA_; k0 += 64) {
    __syncthreads();
    #pragma unroll
    for (int i = 0; i < 4; ++i) {
      int id = t + 256 * i, row = id >> 3, ch = id & 7;
      *(u16x8*)&As[row][ch * 8] = areg[i];
      *(u16x8*)&Bs[row][ch * 8] = breg[i];
    }
    __syncthreads();
    {
      int kn = (k0 + 64 < A_ * DA_) ? k0 + 64 : k0;
      #pragma unroll
      for (int i = 0; i < 4; ++i) {
        int id = t + 256 * i, row = id >> 3, ch = id & 7;
        areg[i] = *(const u16x8*)(Ofu + ((size_t)(mt * 128 + row)) * (A_ * DA_) + kn + ch * 8);
        breg[i] = *(const u16x8*)(Wu + ((size_t)(nt * 128 + row)) * (A_ * DA_) + kn + ch * 8);
      }
    }
    #pragma unroll
    for (int ks = 0; ks < 2; ++ks) {
      bf16x8 af[4], bfr[4];
      #pragma unroll
      for (int mf = 0; mf < 4; ++mf)
        af[mf] = *(const bf16x8*)&As[MO + mf * 16 + x][ks * 32 + g * 8];
      #pragma unroll
      for (int nf = 0; nf < 4; ++nf)
        bfr[nf] = *(const bf16x8*)&Bs[NO + nf * 16 + x][ks * 32 + g * 8];
      #pragma unroll
      for (int mf = 0; mf < 4; ++mf)
        #pragma unroll
        for (int nf = 0; nf < 4; ++nf)
          acc[mf][nf] = __builtin_amdgcn_mfma_f32_16x16x32_bf16(af[mf], bfr[nf], acc[mf][nf], 0, 0, 0);
    }
  }

  #pragma unroll
  for (int nf = 0; nf < 4; ++nf) {
    const int n = nt * 128 + NO + nf * 16 + x;
    const float bval = bo[n];
    #pragma unroll
    for (int mf = 0; mf < 4; ++mf)
      #pragma unroll
      for (int r = 0; r < 4; ++r) {
        int row = mt * 128 + MO + mf * 16 + 4 * g + r;
        Z[(size_t)row * D_ + n] = acc[mf][nf][r] + bval;
      }
  }
}

extern "C" void kernel_launch(void* const* d_in, const int* in_sizes, int n_in,
                              void* d_out, int out_size, void* d_ws, size_t ws_size,
                              hipStream_t stream) {
  const float* x     = (const float*)d_in[0];
  const float* Wq    = (const float*)d_in[1];
  const float* bq    = (const float*)d_in[2];
  const float* Wk    = (const float*)d_in[3];
  const float* bk    = (const float*)d_in[4];
  const float* Wv    = (const float*)d_in[5];
  const float* bv    = (const float*)d_in[6];
  const float* Wr    = (const float*)d_in[7];
  const float* br    = (const float*)d_in[8];
  const float* gamma = (const float*)d_in[9];
  const float* beta  = (const float*)d_in[10];
  const float* Wo    = (const float*)d_in[11];
  const float* bo    = (const float*)d_in[12];
  float* Z = (float*)d_out;

  char* ws = (char*)d_ws;
  float*  partial = (float*)(ws + OFF_PARTIAL);
  int*    idx     = (int*)(ws + OFF_IDX);
  float*  dist    = (float*)(ws + OFF_DIST);
  __bf16* WoT     = (__bf16*)(ws + OFF_WOT);
  __bf16* xb      = (__bf16*)(ws + OFF_XB);
  __bf16* Wt      = (__bf16*)(ws + OFF_WT);
  __bf16* Q       = (__bf16*)(ws + OFF_Q);
  __bf16* Ofin    = (__bf16*)(ws + OFF_OFIN);
  __bf16* K       = (__bf16*)(ws + OFF_K);
  __bf16* Vt      = (__bf16*)(ws + OFF_V);

  k_partial<<<dim3(32, B_), 256, 0, stream>>>(x, partial, xb);
  k_wt<<<dim3(16, 16, 3), 256, 0, stream>>>(Wq, Wk, Wv, Wt);
  k_wto<<<dim3(16, 4), 256, 0, stream>>>(Wo, WoT);
  k_stats<<<B_, 256, 0, stream>>>(partial, Wr, br, gamma, beta, idx, dist);
  k_qkv_mfma<<<dim3(S_ / 64, B_ * A_), 256, 0, stream>>>(xb, Wt, bq, bk, bv, idx, Q, K, Vt);
  k_attn_mfma<<<dim3(S_ / 64, B_ * A_), 256, 0, stream>>>(Q, K, Vt, dist, Ofin);
  k_oproj_mfma<<<dim3(D_ / 128, (B_ * S_) / 128), 256, 0, stream>>>(Ofin, WoT, bo, Z);
}

// Round 17
// 168.360 us; speedup vs baseline: 1.2842x; 1.0090x over previous
//
#include <hip/hip_runtime.h>
#include <math.h>

#define B_ 8
#define S_ 2048
#define D_ 1024
#define H_ 16
#define A_ 4
#define DA_ 64
#define LN_EPS 1e-5f
// 0.125 * log2(e): Q pre-scale so softmax runs in exp2 domain
#define QSCALE 0.1803368801111204f
// fixed softmax reference (log2 units), folded into the QK accumulator init
#define MREF 20.0f

typedef __bf16 bf16x8 __attribute__((ext_vector_type(8)));
typedef __bf16 bf16x4 __attribute__((ext_vector_type(4)));
typedef float f32x4 __attribute__((ext_vector_type(4)));
typedef float f32x16 __attribute__((ext_vector_type(16)));
typedef unsigned short u16x8 __attribute__((ext_vector_type(8)));
typedef unsigned short u16x4 __attribute__((ext_vector_type(4)));

// ---------------- workspace layout (bytes) ----------------
static const size_t OFF_PARTIAL = 0;
static const size_t OFF_IDX     = (size_t)1 << 20;
static const size_t OFF_DIST    = ((size_t)1 << 20) + 1024;
static const size_t OFF_WOT     = ((size_t)1 << 20) + ((size_t)1 << 19);
static const size_t OFF_XB      = (size_t)2 << 20;
static const size_t OFF_OFIN    = OFF_XB;                    // xb dead after qkv
static const size_t OFF_WT      = (size_t)34 << 20;
static const size_t OFF_Q       = (size_t)40 << 20;
static const size_t OFF_K       = (size_t)48 << 20;
static const size_t OFF_V       = (size_t)56 << 20;

// ---------------- kernel 1: column-sum partial over S + bf16 convert ----------------
__global__ __launch_bounds__(256) void k_partial(const float* __restrict__ x,
                                                 float* __restrict__ partial,
                                                 __bf16* __restrict__ xb) {
  const int c = blockIdx.x, b = blockIdx.y, t = threadIdx.x;
  const size_t base = ((size_t)b * S_ + (size_t)c * 64) * D_;
  f32x4 acc = {0.f, 0.f, 0.f, 0.f};
  for (int s = 0; s < 64; ++s) {
    f32x4 v = *(const f32x4*)(x + base + (size_t)s * D_ + 4 * t);
    acc += v;
    bf16x4 o;
    #pragma unroll
    for (int j = 0; j < 4; ++j) o[j] = (__bf16)v[j];
    *(bf16x4*)(xb + base + (size_t)s * D_ + 4 * t) = o;
  }
  *(f32x4*)(partial + ((size_t)b * 32 + c) * D_ + 4 * t) = acc;
}

// ---------------- kernel 1b: transpose QKV weights to bf16 [m][n][k] ----------------
__global__ __launch_bounds__(256) void k_wt(const float* __restrict__ Wq,
                                            const float* __restrict__ Wk,
                                            const float* __restrict__ Wv,
                                            __bf16* __restrict__ Wt) {
  __shared__ float tsh[64][65];
  const int n0 = blockIdx.x * 64, k0 = blockIdx.y * 64, z = blockIdx.z;
  const float* W = (z == 0) ? Wq : (z == 1) ? Wk : Wv;
  const int t = threadIdx.x;
  #pragma unroll
  for (int i = 0; i < 4; ++i) {
    int r = i * 16 + (t >> 4), c = (t & 15) * 4;
    f32x4 v = *(const f32x4*)(W + (size_t)(k0 + r) * (H_ * DA_) + n0 + c);
    tsh[r][c + 0] = v[0]; tsh[r][c + 1] = v[1]; tsh[r][c + 2] = v[2]; tsh[r][c + 3] = v[3];
  }
  __syncthreads();
  #pragma unroll
  for (int i = 0; i < 4; ++i) {
    int n = i * 16 + (t >> 4), kc = (t & 15) * 4;
    bf16x4 o;
    #pragma unroll
    for (int j = 0; j < 4; ++j) o[j] = (__bf16)tsh[kc + j][n];
    *(bf16x4*)(Wt + (size_t)z * 1048576 + (size_t)(n0 + n) * 1024 + k0 + kc) = o;
  }
}

// ---------------- kernel 1c: transpose Wo [256][1024] -> WoT bf16 [1024][256] ----------------
__global__ __launch_bounds__(256) void k_wto(const float* __restrict__ Wo,
                                             __bf16* __restrict__ WoT) {
  __shared__ float tsh[64][65];
  const int n0 = blockIdx.x * 64, k0 = blockIdx.y * 64;
  const int t = threadIdx.x;
  #pragma unroll
  for (int i = 0; i < 4; ++i) {
    int r = i * 16 + (t >> 4), c = (t & 15) * 4;
    f32x4 v = *(const f32x4*)(Wo + (size_t)(k0 + r) * D_ + n0 + c);
    tsh[r][c + 0] = v[0]; tsh[r][c + 1] = v[1]; tsh[r][c + 2] = v[2]; tsh[r][c + 3] = v[3];
  }
  __syncthreads();
  #pragma unroll
  for (int i = 0; i < 4; ++i) {
    int n = i * 16 + (t >> 4), kc = (t & 15) * 4;
    bf16x4 o;
    #pragma unroll
    for (int j = 0; j < 4; ++j) o[j] = (__bf16)tsh[kc + j][n];
    *(bf16x4*)(WoT + (size_t)(n0 + n) * (A_ * DA_) + k0 + kc) = o;
  }
}

// ---------------- kernel 2: xbar -> r -> LN -> softmax -> top4 ----------------
__global__ __launch_bounds__(256) void k_stats(const float* __restrict__ partial,
                                               const float* __restrict__ Wr,
                                               const float* __restrict__ br,
                                               const float* __restrict__ gamma,
                                               const float* __restrict__ beta,
                                               int* __restrict__ idx_out,
                                               float* __restrict__ dist_out) {
  __shared__ float xbar[D_];
  __shared__ float rsh[H_];
  const int b = blockIdx.x, t = threadIdx.x;
  #pragma unroll
  for (int j = 0; j < 4; ++j) {
    int d = j * 256 + t;
    float s = 0.f;
    for (int c = 0; c < 32; ++c) s += partial[((size_t)b * 32 + c) * D_ + d];
    xbar[d] = s * (1.0f / S_);
  }
  __syncthreads();
  const int w = t >> 6, lane = t & 63;
  #pragma unroll
  for (int i = 0; i < 4; ++i) {
    int h = w * 4 + i;
    float s = 0.f;
    #pragma unroll
    for (int j = 0; j < 16; ++j) {
      int d = j * 64 + lane;
      s += xbar[d] * Wr[d * H_ + h];
    }
    for (int off = 32; off; off >>= 1) s += __shfl_down(s, off);
    if (lane == 0) rsh[h] = s + br[h];
  }
  __syncthreads();
  if (t == 0) {
    float r[H_];
    float mu = 0.f;
    for (int h = 0; h < H_; ++h) { r[h] = rsh[h]; mu += r[h]; }
    mu *= (1.0f / H_);
    float var = 0.f;
    for (int h = 0; h < H_; ++h) { float d = r[h] - mu; var += d * d; }
    var *= (1.0f / H_);
    float inv = rsqrtf(var + LN_EPS);
    float rn[H_], ex[H_];
    float mx = -1e30f;
    for (int h = 0; h < H_; ++h) {
      rn[h] = (r[h] - mu) * inv * gamma[h] + beta[h];
      mx = fmaxf(mx, rn[h]);
    }
    float sum = 0.f;
    for (int h = 0; h < H_; ++h) { ex[h] = expf(rn[h] - mx); sum += ex[h]; }
    int sel[A_];
    bool used[H_] = {false};
    for (int a = 0; a < A_; ++a) {
      int best = 0; float bv = -1.f;
      for (int h = 0; h < H_; ++h)
        if (!used[h] && ex[h] > bv) { bv = ex[h]; best = h; }
      used[best] = true; sel[a] = best;
    }
    for (int i = 0; i < A_; ++i)
      for (int j = i + 1; j < A_; ++j)
        if (sel[j] < sel[i]) { int tmp = sel[i]; sel[i] = sel[j]; sel[j] = tmp; }
    float invsum = 1.0f / sum;
    for (int a = 0; a < A_; ++a) {
      idx_out[b * A_ + a] = sel[a];
      dist_out[b * A_ + a] = ex[sel[a]] * invsum;
    }
  }
}

// ---------------- kernel 3: QKV projection, bf16 MFMA ----------------
__global__ __launch_bounds__(256) void k_qkv_mfma(const __bf16* __restrict__ xb,
                                                  const __bf16* __restrict__ Wt,
                                                  const float* __restrict__ bq,
                                                  const float* __restrict__ bk,
                                                  const float* __restrict__ bv,
                                                  const int* __restrict__ idx,
                                                  __bf16* __restrict__ Q,
                                                  __bf16* __restrict__ K,
                                                  __bf16* __restrict__ Vt_g) {
  __shared__ unsigned short As[64][72];
  __shared__ unsigned short Bs[192][72];
  const int qt = blockIdx.x, ba = blockIdx.y;
  const int b = ba >> 2;
  const int head64 = idx[ba] * 64;
  const int t = threadIdx.x;
  const int w = t >> 6, l = t & 63, x = l & 15, g = l >> 4;
  const int MO = (w >> 1) * 32, NO = (w & 1) * 96;

  const unsigned short* xbu = (const unsigned short*)xb;
  const unsigned short* Wtu = (const unsigned short*)Wt;
  const size_t xbase = ((size_t)b * S_ + (size_t)qt * 64) * D_;

  u16x8 areg[2], breg[6];
  #pragma unroll
  for (int i = 0; i < 2; ++i) {
    int id = t + 256 * i, row = id >> 3, ch = id & 7;
    areg[i] = *(const u16x8*)(xbu + xbase + (size_t)row * D_ + ch * 8);
  }
  #pragma unroll
  for (int i = 0; i < 6; ++i) {
    int id = t + 256 * i, row = id >> 3, ch = id & 7;
    int m = row >> 6, nn = row & 63;
    breg[i] = *(const u16x8*)(Wtu + (size_t)m * 1048576 +
                              (size_t)(head64 + nn) * 1024 + ch * 8);
  }

  f32x4 acc[2][6];
  #pragma unroll
  for (int mf = 0; mf < 2; ++mf)
    #pragma unroll
    for (int nf = 0; nf < 6; ++nf) acc[mf][nf] = (f32x4){0.f, 0.f, 0.f, 0.f};

  for (int k0 = 0; k0 < D_; k0 += 64) {
    __syncthreads();
    #pragma unroll
    for (int i = 0; i < 2; ++i) {
      int id = t + 256 * i, row = id >> 3, ch = id & 7;
      *(u16x8*)&As[row][ch * 8] = areg[i];
    }
    #pragma unroll
    for (int i = 0; i < 6; ++i) {
      int id = t + 256 * i, row = id >> 3, ch = id & 7;
      *(u16x8*)&Bs[row][ch * 8] = breg[i];
    }
    __syncthreads();
    {
      int kn = (k0 + 64 < D_) ? k0 + 64 : k0;
      #pragma unroll
      for (int i = 0; i < 2; ++i) {
        int id = t + 256 * i, row = id >> 3, ch = id & 7;
        areg[i] = *(const u16x8*)(xbu + xbase + (size_t)row * D_ + kn + ch * 8);
      }
      #pragma unroll
      for (int i = 0; i < 6; ++i) {
        int id = t + 256 * i, row = id >> 3, ch = id & 7;
        int m = row >> 6, nn = row & 63;
        breg[i] = *(const u16x8*)(Wtu + (size_t)m * 1048576 +
                                  (size_t)(head64 + nn) * 1024 + kn + ch * 8);
      }
    }
    #pragma unroll
    for (int ks = 0; ks < 2; ++ks) {
      bf16x8 af[2], bfr[6];
      #pragma unroll
      for (int mf = 0; mf < 2; ++mf)
        af[mf] = *(const bf16x8*)&As[MO + mf * 16 + x][ks * 32 + g * 8];
      #pragma unroll
      for (int nf = 0; nf < 6; ++nf)
        bfr[nf] = *(const bf16x8*)&Bs[NO + nf * 16 + x][ks * 32 + g * 8];
      #pragma unroll
      for (int mf = 0; mf < 2; ++mf)
        #pragma unroll
        for (int nf = 0; nf < 6; ++nf)
          acc[mf][nf] = __builtin_amdgcn_mfma_f32_16x16x32_bf16(af[mf], bfr[nf], acc[mf][nf], 0, 0, 0);
    }
  }

  // ---- epilogue: Q and K direct (row-major); V via LDS bounce, transposed ----
  #pragma unroll
  for (int nf = 0; nf < 6; ++nf) {
    const int n = NO + nf * 16;
    const int m = n >> 6;
    if (m == 2) continue;                 // V handled by the bounce below
    const float* bias = (m == 0) ? bq : bk;
    __bf16* out = (m == 0) ? Q : K;
    const float sc = (m == 0) ? QSCALE : 1.0f;
    const int nn = (n & 63) + x;
    const float bval = bias[head64 + nn];
    #pragma unroll
    for (int mf = 0; mf < 2; ++mf)
      #pragma unroll
      for (int r = 0; r < 4; ++r) {
        int srow = qt * 64 + MO + mf * 16 + 4 * g + r;
        float val = (acc[mf][nf][r] + bval) * sc;
        out[((size_t)ba * S_ + srow) * DA_ + nn] = (__bf16)val;
      }
  }

  __syncthreads();                        // As dead (main loop done)
  if (w & 1) {                            // waves 1,3 own V (nf=2..5)
    #pragma unroll
    for (int nf = 2; nf < 6; ++nf) {
      const int da = (nf - 2) * 16 + x;
      const float bval = bv[head64 + da];
      #pragma unroll
      for (int mf = 0; mf < 2; ++mf)
        #pragma unroll
        for (int r = 0; r < 4; ++r) {
          int ls = MO + mf * 16 + 4 * g + r;   // local s-row 0..63
          __bf16 vb = (__bf16)(acc[mf][nf][r] + bval);
          As[da][ls] = __builtin_bit_cast(unsigned short, vb);
        }
    }
  }
  __syncthreads();
  {
    unsigned short* Vtu = (unsigned short*)Vt_g;
    const int vrow = t >> 3, vch = t & 7;
    u16x8 v0 = *(const u16x8*)&As[vrow][vch * 8];
    u16x8 v1 = *(const u16x8*)&As[vrow + 32][vch * 8];
    const size_t vb0 = (size_t)ba * DA_ * S_;
    *(u16x8*)(Vtu + vb0 + (size_t)vrow * S_ + qt * 64 + vch * 8) = v0;
    *(u16x8*)(Vtu + vb0 + (size_t)(vrow + 32) * S_ + qt * 64 + vch * 8) = v1;
  }
}

// ---------------- kernel 4: flash attention, bf16 MFMA 32x32x16 ----------------
// grid (S/64=32, B*A=32) = 1024 blocks (4/CU), block 256 (4 waves).
// Wave w: kv-half kvh=w&1, q-half qh=w>>1. QK: s = mfma_32x32x16(K, Q)
// (swapped; D[kv][q], lane col q=qh*32+(l&31), rows kv). PV wave-local over
// own kv-half; cross-kvh O reduced once in epilogue via LDS (Ks/Vt reused).
// Fixed-reference softmax (-MREF in C-init); async reg dbuf staging;
// V from global Vt[ba][da][s]; chunk-XOR LDS swizzles throughout.
__global__ __launch_bounds__(256, 4) void k_attn_mfma(const __bf16* __restrict__ Qg,
                                                      const __bf16* __restrict__ Kg,
                                                      const __bf16* __restrict__ Vtg,
                                                      const float* __restrict__ dist,
                                                      __bf16* __restrict__ Ofin) {
  __shared__ unsigned short QPs[64 * 72];  // Q stage (row*64), P (row*72), lsh (f32)
  __shared__ unsigned short Ks[64 * 64];   // K tile; epilogue: obuf dh=0 (8KB f32)
  __shared__ unsigned short Vt[64 * 64];   // V tile; epilogue: obuf dh=1 (8KB f32)

  const int qt = blockIdx.x, ba = blockIdx.y;
  const int b = ba >> 2, a = ba & 3;
  const int t = threadIdx.x;
  const int w = t >> 6, l = t & 63;
  const int c = l & 31, hb = l >> 5;       // 32-col index, k-half
  const int kvh = w & 1, qh = w >> 1;

  const unsigned short* Qgu = (const unsigned short*)Qg;
  const unsigned short* Kgu = (const unsigned short*)Kg;
  const unsigned short* Vgu = (const unsigned short*)Vtg;

  const size_t kvbase = (size_t)ba * S_ * DA_;   // K base ([s][da])
  const size_t vbase  = (size_t)ba * DA_ * S_;   // Vt base ([da][s])

  const int krow = t >> 3, kch = t & 7;

  // ---- prologue: issue K/V loads for tile 0 ----
  u16x8 kreg0, kreg1, vreg0, vreg1;
  kreg0 = *(const u16x8*)(Kgu + kvbase + (size_t)(krow) * 64 + kch * 8);
  kreg1 = *(const u16x8*)(Kgu + kvbase + (size_t)(krow + 32) * 64 + kch * 8);
  vreg0 = *(const u16x8*)(Vgu + vbase + (size_t)krow * S_ + kch * 8);
  vreg1 = *(const u16x8*)(Vgu + vbase + (size_t)(krow + 32) * S_ + kch * 8);

  // ---- stage Q tile (64 x 64) into QPs, chunk-XOR swizzle ----
  {
    const size_t qbase = ((size_t)ba * S_ + (size_t)qt * 64) * DA_;
    #pragma unroll
    for (int i = 0; i < 2; ++i) {
      int row = (t >> 3) + 32 * i;
      int ch = t & 7;
      u16x8 v = *(const u16x8*)(Qgu + qbase + (size_t)row * 64 + ch * 8);
      *(u16x8*)&QPs[row * 64 + ((ch ^ (row & 7)) << 3)] = v;
    }
  }
  __syncthreads();

  // ---- hoist Q fragments: qf[ks] = Q[q = qh*32+c][d = ks*16 + hb*8 ..] ----
  bf16x8 qf[4];
  {
    int q = qh * 32 + c;
    #pragma unroll
    for (int ks = 0; ks < 4; ++ks) {
      int ch = (ks * 2 + hb) ^ (q & 7);
      qf[ks] = *(const bf16x8*)&QPs[q * 64 + (ch << 3)];
    }
  }

  f32x16 o0, o1;                          // O partial: [q rows][da = dh*32+c]
  #pragma unroll
  for (int i = 0; i < 16; ++i) { o0[i] = 0.f; o1[i] = 0.f; }
  float l_lane = 0.f;

  for (int kt = 0; kt < 32; ++kt) {
    __syncthreads();  // prior reads (incl. Q hoist on iter0) done
    *(u16x8*)&Ks[krow * 64 + ((kch ^ (krow & 7)) << 3)] = kreg0;
    *(u16x8*)&Vt[krow * 64 + ((kch ^ (krow & 7)) << 3)] = vreg0;
    {
      int row1 = krow + 32;
      *(u16x8*)&Ks[row1 * 64 + ((kch ^ (row1 & 7)) << 3)] = kreg1;
      *(u16x8*)&Vt[row1 * 64 + ((kch ^ (row1 & 7)) << 3)] = vreg1;
    }
    __syncthreads();

    // ---- issue async loads for tile kt+1 ----
    {
      int ktn = (kt + 1 < 32) ? kt + 1 : kt;
      kreg0 = *(const u16x8*)(Kgu + kvbase + (size_t)(ktn * 64 + krow) * 64 + kch * 8);
      kreg1 = *(const u16x8*)(Kgu + kvbase + (size_t)(ktn * 64 + krow + 32) * 64 + kch * 8);
      vreg0 = *(const u16x8*)(Vgu + vbase + (size_t)krow * S_ + ktn * 64 + kch * 8);
      vreg1 = *(const u16x8*)(Vgu + vbase + (size_t)(krow + 32) * S_ + ktn * 64 + kch * 8);
    }

    // ---- QK^T swapped, 32x32x16: s[kv = kvh-half rows][q = qh*32+c] ----
    f32x16 s;
    #pragma unroll
    for (int i = 0; i < 16; ++i) s[i] = -MREF;
    #pragma unroll
    for (int ks = 0; ks < 4; ++ks) {
      int kv = kvh * 32 + c;
      int ch = (ks * 2 + hb) ^ (kv & 7);
      bf16x8 kf = *(const bf16x8*)&Ks[kv * 64 + (ch << 3)];
      s = __builtin_amdgcn_mfma_f32_32x32x16_bf16(kf, qf[ks], s, 0, 0, 0);
    }

    // ---- softmax numerator: p = exp2(s); single per-lane l partial ----
    float rs = 0.f;
    #pragma unroll
    for (int i = 0; i < 16; ++i) {
      float p = exp2f(s[i]);
      s[i] = p;
      rs += p;
    }
    l_lane += rs;

    // ---- P -> LDS: rows q = qh*32+c, 4 packed b64 (kv consecutive) ----
    #pragma unroll
    for (int rg = 0; rg < 4; ++rg) {
      u16x4 pk;
      #pragma unroll
      for (int rr = 0; rr < 4; ++rr) {
        __bf16 pb = (__bf16)s[rg * 4 + rr];
        pk[rr] = __builtin_bit_cast(unsigned short, pb);
      }
      int kvb = kvh * 32 + 8 * rg + 4 * hb;
      *(u16x4*)&QPs[(qh * 32 + c) * 72 + kvb] = pk;
    }

    // ---- PV wave-local: O[q][da] += P[q][own kv-half] @ V ----
    #pragma unroll
    for (int ks2 = 0; ks2 < 2; ++ks2) {
      // A = P: lane row q = qh*32+c, k = kv = kvh*32 + ks2*16 + hb*8 ..
      bf16x8 pf = *(const bf16x8*)&QPs[(qh * 32 + c) * 72 + kvh * 32 + ks2 * 16 + hb * 8];
      // B = V: lane col da = dh*32+c, k = same kv range (from Vt[da][kv])
      #pragma unroll
      for (int dh = 0; dh < 2; ++dh) {
        int da = dh * 32 + c;
        int ch = (kvh * 4 + ks2 * 2 + hb) ^ (da & 7);
        bf16x8 vf = *(const bf16x8*)&Vt[da * 64 + (ch << 3)];
        if (dh == 0) o0 = __builtin_amdgcn_mfma_f32_32x32x16_bf16(pf, vf, o0, 0, 0, 0);
        else         o1 = __builtin_amdgcn_mfma_f32_32x32x16_bf16(pf, vf, o1, 0, 0, 0);
      }
    }
  }

  // ---- epilogue ----
  const float dd = dist[ba];
  float* lshf = (float*)QPs;              // P dead; 192 floats used
  float* ob0  = (float*)Ks;               // K dead; 2048 floats (8KB)
  float* ob1  = (float*)Vt;               // V dead; 2048 floats (8KB)

  __syncthreads();                        // all loop LDS reads done
  // l partial: lane covers q = qh*32+c over its 16 kv rows; xor32 -> kvh-half
  {
    float lf = l_lane + __shfl_xor(l_lane, 32);
    lshf[kvh * 64 + qh * 32 + c] = lf;    // duplicate write from hb=0/1, same value
  }
  // kvh=1 waves export O partials
  if (kvh == 1) {
    #pragma unroll
    for (int i = 0; i < 16; ++i) {
      ob0[qh * 1024 + l * 16 + i] = o0[i];
      ob1[qh * 1024 + l * 16 + i] = o1[i];
    }
  }
  __syncthreads();
  // linv table
  if (t < 64) {
    float lv = lshf[t] + lshf[64 + t];
    lshf[128 + t] = dd / lv;
  }
  if (kvh == 0) {
    #pragma unroll
    for (int i = 0; i < 16; ++i) {
      o0[i] += ob0[qh * 1024 + l * 16 + i];
      o1[i] += ob1[qh * 1024 + l * 16 + i];
    }
  }
  __syncthreads();
  if (kvh == 0) {
    // lane holds O[q = qh*32 + (reg&3)+8*(reg>>2)+4*hb][da = dh*32 + c]
    #pragma unroll
    for (int rg = 0; rg < 4; ++rg) {
      int qloc = qh * 32 + 8 * rg + 4 * hb;            // 4 consecutive q
      f32x4 linv = *(const f32x4*)&lshf[128 + qloc];
      #pragma unroll
      for (int rr = 0; rr < 4; ++rr) {
        int row = qt * 64 + qloc + rr;
        size_t obase = ((size_t)b * S_ + row) * (A_ * DA_) + a * DA_;
        Ofin[obase + c]      = (__bf16)(o0[rg * 4 + rr] * linv[rr]);
        Ofin[obase + 32 + c] = (__bf16)(o1[rg * 4 + rr] * linv[rr]);
      }
    }
  }
}

// ---------------- kernel 5: output projection, bf16 MFMA (async reg dbuf) ----------------
__global__ __launch_bounds__(256) void k_oproj_mfma(const __bf16* __restrict__ Of,
                                                    const __bf16* __restrict__ WoT,
                                                    const float* __restrict__ bo,
                                                    float* __restrict__ Z) {
  __shared__ unsigned short As[128][72];
  __shared__ unsigned short Bs[128][72];
  const int nt = blockIdx.x, mt = blockIdx.y;
  const int t = threadIdx.x;
  const int w = t >> 6, l = t & 63, x = l & 15, g = l >> 4;
  const int MO = (w >> 1) * 64, NO = (w & 1) * 64;

  const unsigned short* Ofu = (const unsigned short*)Of;
  const unsigned short* Wu  = (const unsigned short*)WoT;

  u16x8 areg[4], breg[4];
  #pragma unroll
  for (int i = 0; i < 4; ++i) {
    int id = t + 256 * i, row = id >> 3, ch = id & 7;
    areg[i] = *(const u16x8*)(Ofu + ((size_t)(mt * 128 + row)) * (A_ * DA_) + ch * 8);
    breg[i] = *(const u16x8*)(Wu + ((size_t)(nt * 128 + row)) * (A_ * DA_) + ch * 8);
  }

  f32x4 acc[4][4];
  #pragma unroll
  for (int mf = 0; mf < 4; ++mf)
    #pragma unroll
    for (int nf = 0; nf < 4; ++nf) acc[mf][nf] = (f32x4){0.f, 0.f, 0.f, 0.f};

  for (int k0 = 0; k0 < A_ * DA_; k0 += 64) {
    __syncthreads();
    #pragma unroll
    for (int i = 0; i < 4; ++i) {
      int id = t + 256 * i, row = id >> 3, ch = id & 7;
      *(u16x8*)&As[row][ch * 8] = areg[i];
      *(u16x8*)&Bs[row][ch * 8] = breg[i];
    }
    __syncthreads();
    {
      int kn = (k0 + 64 < A_ * DA_) ? k0 + 64 : k0;
      #pragma unroll
      for (int i = 0; i < 4; ++i) {
        int id = t + 256 * i, row = id >> 3, ch = id & 7;
        areg[i] = *(const u16x8*)(Ofu + ((size_t)(mt * 128 + row)) * (A_ * DA_) + kn + ch * 8);
        breg[i] = *(const u16x8*)(Wu + ((size_t)(nt * 128 + row)) * (A_ * DA_) + kn + ch * 8);
      }
    }
    #pragma unroll
    for (int ks = 0; ks < 2; ++ks) {
      bf16x8 af[4], bfr[4];
      #pragma unroll
      for (int mf = 0; mf < 4; ++mf)
        af[mf] = *(const bf16x8*)&As[MO + mf * 16 + x][ks * 32 + g * 8];
      #pragma unroll
      for (int nf = 0; nf < 4; ++nf)
        bfr[nf] = *(const bf16x8*)&Bs[NO + nf * 16 + x][ks * 32 + g * 8];
      #pragma unroll
      for (int mf = 0; mf < 4; ++mf)
        #pragma unroll
        for (int nf = 0; nf < 4; ++nf)
          acc[mf][nf] = __builtin_amdgcn_mfma_f32_16x16x32_bf16(af[mf], bfr[nf], acc[mf][nf], 0, 0, 0);
    }
  }

  #pragma unroll
  for (int nf = 0; nf < 4; ++nf) {
    const int n = nt * 128 + NO + nf * 16 + x;
    const float bval = bo[n];
    #pragma unroll
    for (int mf = 0; mf < 4; ++mf)
      #pragma unroll
      for (int r = 0; r < 4; ++r) {
        int row = mt * 128 + MO + mf * 16 + 4 * g + r;
        Z[(size_t)row * D_ + n] = acc[mf][nf][r] + bval;
      }
  }
}

extern "C" void kernel_launch(void* const* d_in, const int* in_sizes, int n_in,
                              void* d_out, int out_size, void* d_ws, size_t ws_size,
                              hipStream_t stream) {
  const float* x     = (const float*)d_in[0];
  const float* Wq    = (const float*)d_in[1];
  const float* bq    = (const float*)d_in[2];
  const float* Wk    = (const float*)d_in[3];
  const float* bk    = (const float*)d_in[4];
  const float* Wv    = (const float*)d_in[5];
  const float* bv    = (const float*)d_in[6];
  const float* Wr    = (const float*)d_in[7];
  const float* br    = (const float*)d_in[8];
  const float* gamma = (const float*)d_in[9];
  const float* beta  = (const float*)d_in[10];
  const float* Wo    = (const float*)d_in[11];
  const float* bo    = (const float*)d_in[12];
  float* Z = (float*)d_out;

  char* ws = (char*)d_ws;
  float*  partial = (float*)(ws + OFF_PARTIAL);
  int*    idx     = (int*)(ws + OFF_IDX);
  float*  dist    = (float*)(ws + OFF_DIST);
  __bf16* WoT     = (__bf16*)(ws + OFF_WOT);
  __bf16* xb      = (__bf16*)(ws + OFF_XB);
  __bf16* Wt      = (__bf16*)(ws + OFF_WT);
  __bf16* Q       = (__bf16*)(ws + OFF_Q);
  __bf16* Ofin    = (__bf16*)(ws + OFF_OFIN);
  __bf16* K       = (__bf16*)(ws + OFF_K);
  __bf16* Vt      = (__bf16*)(ws + OFF_V);

  k_partial<<<dim3(32, B_), 256, 0, stream>>>(x, partial, xb);
  k_wt<<<dim3(16, 16, 3), 256, 0, stream>>>(Wq, Wk, Wv, Wt);
  k_wto<<<dim3(16, 4), 256, 0, stream>>>(Wo, WoT);
  k_stats<<<B_, 256, 0, stream>>>(partial, Wr, br, gamma, beta, idx, dist);
  k_qkv_mfma<<<dim3(S_ / 64, B_ * A_), 256, 0, stream>>>(xb, Wt, bq, bk, bv, idx, Q, K, Vt);
  k_attn_mfma<<<dim3(S_ / 64, B_ * A_), 256, 0, stream>>>(Q, K, Vt, dist, Ofin);
  k_oproj_mfma<<<dim3(D_ / 128, (B_ * S_) / 128), 256, 0, stream>>>(Ofin, WoT, bo, Z);
}